// Round 17
// baseline (213.206 us; speedup 1.0000x reference)
//
#include <hip/hip_runtime.h>
#include <stdint.h>

// RPN rotated-NMS post-processor, MI355X. Round 17: node-count reduction
// 7 -> 5 via last-block fusion: thresh folded into k_hist, Jacobi NMS folded
// into k_iou (device-scope fence + done-counter pattern). Bodies otherwise r16.

#define NBATCH 4
#define AANCH 15
#define HDIM 200
#define WDIM 200
#define MTOT (AANCH*HDIM*WDIM)   // 600000
#define KTOP 1000
#define POSTN 300
#define NBINS 16384
#define CAND_CAP 2048
#define NWORDS 16                // ceil(1000/64)
#define NMS_TH 0.7f
#define BPB 75                   // blocks per batch for hist
#define CHUNK (MTOT/BPB)         // 8000
#define IOU_ROWS 4               // i-rows per iou block
#define IOU_BPB 250              // iou blocks per batch
#define IOU_WPB (IOU_ROWS*NWORDS) // 64 mask words per iou block
#define QCAP 4096                // provable max survivors (4 rows x <=1000 j)
#define NQ4 (MTOT/4)             // 150000 float4 per batch
#define CBLK ((NQ4+255)/256)     // 586 compact blocks per batch

// ---------------- ws layout ----------------
constexpr size_t OFF_HIST = 0;
constexpr size_t SZ_HIST  = (size_t)NBATCH*NBINS*4;                 // 262144
constexpr size_t OFF_CNT  = OFF_HIST + SZ_HIST;
constexpr size_t OFF_THR  = OFF_CNT + 256;   // thr[4] @ +0, done_hist[4] @ +64, done_iou[4] @ +128
constexpr size_t OFF_CAND = OFF_THR + 256;                          // 262656 B zeroed
constexpr size_t OFF_PROP = OFF_CAND + (size_t)NBATCH*CAND_CAP*8;
constexpr size_t OFF_SCORE= OFF_PROP + (size_t)NBATCH*KTOP*5*4;
constexpr size_t OFF_CORN = OFF_SCORE+ (size_t)NBATCH*KTOP*4;
constexpr size_t OFF_AREA = OFF_CORN + (size_t)NBATCH*KTOP*8*4;
constexpr size_t OFF_VALID= OFF_AREA + (size_t)NBATCH*KTOP*4;
constexpr size_t OFF_XYR  = OFF_VALID+ (size_t)NBATCH*KTOP*4;
constexpr size_t OFF_MASK = OFF_XYR  + (size_t)NBATCH*KTOP*16;      // maskT [n][l][row]

constexpr int ZERO_U4 = (int)(OFF_CAND / 16);   // 16416 uint4 (hist+cnt+thr+done)

__device__ __forceinline__ float sigmoid_ref(float x) {
  return 1.0f / (1.0f + expf(-x));
}

// ---------------- zero scratch header ----------------
__global__ __launch_bounds__(256) void k_zero(uint4* __restrict__ p) {
  int t = blockIdx.x*256 + threadIdx.x;
  if (t < ZERO_U4) p[t] = make_uint4(0u,0u,0u,0u);
}

// ---------------- histogram (LDS-privatized) + last-block threshold scan ----------------
__global__ __launch_bounds__(256) void k_hist(const float* __restrict__ obj,
                                              uint32_t* hist,
                                              uint32_t* thr,
                                              uint32_t* done_hist) {
  __shared__ uint32_t h[NBINS];
  __shared__ uint32_t ps[256];
  __shared__ uint32_t lastf;
  for (int i = threadIdx.x; i < NBINS; i += 256) h[i] = 0;
  __syncthreads();
  int n = blockIdx.x / BPB, c = blockIdx.x % BPB;
  int tid = threadIdx.x;
  const float4* p = (const float4*)(obj + (size_t)n*MTOT + (size_t)c*CHUNK);
  const int nq = CHUNK/4;
  for (int q = tid; q < nq; q += 256) {
    float4 v = p[q];
    #pragma unroll
    for (int k = 0; k < 4; ++k) {
      float x = (&v.x)[k];
      uint32_t bits = __float_as_uint(sigmoid_ref(x));
      uint32_t bin = bits >> 16; if (bin > NBINS-1) bin = NBINS-1;
      atomicAdd(&h[bin], 1u);
    }
  }
  __syncthreads();
  uint32_t* hb = &hist[n*NBINS];
  for (int i = tid; i < NBINS; i += 256) {
    uint32_t v = h[i];
    if (v) atomicAdd(&hb[i], v);
  }
  // ---- last-block-per-batch threshold scan ----
  __threadfence();
  if (tid == 0) lastf = (atomicAdd(&done_hist[n], 1u) == BPB-1) ? 1u : 0u;
  __syncthreads();
  if (!lastf) return;
  __threadfence();
  // atomic reads (coherent point): hist was written only by atomics
  uint32_t s = 0;
  for (int b = tid*64; b < tid*64+64; ++b) s += atomicAdd(&hb[b], 0u);
  ps[tid] = s;
  __syncthreads();
  if (tid == 0) {
    uint32_t cum = 0; int cidx = -1;
    for (int cc = 255; cc >= 0; --cc) {
      if (cum + ps[cc] >= KTOP) { cidx = cc; break; }
      cum += ps[cc];
    }
    if (cidx < 0) { thr[n] = 0u; return; }
    int b = cidx*64+63;
    for (; b >= cidx*64; --b) { cum += atomicAdd(&hb[b], 0u); if (cum >= KTOP) break; }
    thr[n] = (uint32_t)(b < 0 ? 0 : b);
  }
}

// ---------------- compact: float4 loads + block-aggregated atomic ----------------
__global__ __launch_bounds__(256) void k_compact(const float* __restrict__ obj,
                                                 const uint32_t* __restrict__ thr,
                                                 uint64_t* __restrict__ cand,
                                                 uint32_t* __restrict__ cnt) {
  __shared__ uint32_t wtot[4];
  __shared__ uint32_t gbase;
  int n = blockIdx.x / CBLK, c = blockIdx.x % CBLK;
  int tid = threadIdx.x, wv = tid >> 6, lane = tid & 63;
  int q = c*256 + tid;                 // float4 index within batch
  uint32_t th = thr[n];
  bool hit0=false, hit1=false, hit2=false, hit3=false;
  uint32_t bits[4], fidx[4];
  if (q < NQ4) {
    float4 v = ((const float4*)(obj + (size_t)n*MTOT))[q];
    #pragma unroll
    for (int k = 0; k < 4; ++k) {
      float x = (&v.x)[k];
      uint32_t b = __float_as_uint(sigmoid_ref(x));
      uint32_t bin = b >> 16; if (bin > NBINS-1) bin = NBINS-1;
      bits[k] = b;
      int rem = q*4 + k;               // element index within batch
      int hw = rem % (HDIM*WDIM);
      int a  = rem / (HDIM*WDIM);
      fidx[k] = (uint32_t)(hw*AANCH + a);
      bool hk = (bin >= th);
      if (k == 0) hit0 = hk; else if (k == 1) hit1 = hk;
      else if (k == 2) hit2 = hk; else hit3 = hk;
    }
  }
  unsigned long long m0 = __ballot(hit0);
  unsigned long long m1 = __ballot(hit1);
  unsigned long long m2 = __ballot(hit2);
  unsigned long long m3 = __ballot(hit3);
  if (lane == 0)
    wtot[wv] = (uint32_t)(__popcll(m0)+__popcll(m1)+__popcll(m2)+__popcll(m3));
  __syncthreads();
  if (tid == 0) {
    uint32_t t0 = wtot[0], t1 = wtot[1], t2 = wtot[2], t3 = wtot[3];
    uint32_t tot = t0+t1+t2+t3;
    gbase = tot ? atomicAdd(&cnt[n], tot) : 0u;
    wtot[0] = 0; wtot[1] = t0; wtot[2] = t0+t1; wtot[3] = t0+t1+t2;
  }
  __syncthreads();
  uint32_t base = gbase + wtot[wv];
  unsigned long long below = (1ull << lane) - 1ull;
  uint32_t off = 0;
  bool hits[4] = {hit0, hit1, hit2, hit3};
  unsigned long long ms[4] = {m0, m1, m2, m3};
  #pragma unroll
  for (int k = 0; k < 4; ++k) {
    if (hits[k]) {
      uint32_t p = base + off + (uint32_t)__popcll(ms[k] & below);
      if (p < CAND_CAP)
        cand[(size_t)n*CAND_CAP + p] = ((uint64_t)bits[k] << 32) | (uint32_t)(~fidx[k]);
    }
    off += (uint32_t)__popcll(ms[k]);
  }
}

// ---------------- register compare-exchange for wave-local bitonic ----------------
__device__ __forceinline__ uint64_t cex64(uint64_t v, int i, int len, int str, int lane) {
  uint64_t p = __shfl_xor(v, str);
  bool up = ((i & len) == 0);
  bool lower = ((lane & str) == 0);
  uint64_t mn = (v < p) ? v : p;
  uint64_t mx = (v < p) ? p : v;
  return (up == lower) ? mn : mx;
}

// ---------------- hybrid bitonic sort (register wave-local phases) + decode ----------------
__global__ __launch_bounds__(1024) void k_sortdec(const uint64_t* __restrict__ cand,
                                                  const uint32_t* __restrict__ cnt,
                                                  const float* __restrict__ breg,
                                                  const float* __restrict__ anch,
                                                  float* __restrict__ prop,
                                                  float* __restrict__ score,
                                                  float* __restrict__ corn,
                                                  float* __restrict__ area,
                                                  float4* __restrict__ xyr,
                                                  uint32_t* __restrict__ validf) {
  __shared__ uint64_t sk[CAND_CAP];
  int n = blockIdx.x, tid = threadIdx.x;
  int lane = tid & 63, wv = tid >> 6;
  uint32_t c = cnt[n]; if (c > CAND_CAP) c = CAND_CAP;
  for (int i = tid; i < CAND_CAP; i += 1024)
    sk[i] = (i < (int)c) ? cand[(size_t)n*CAND_CAP + i] : 0ull;
  __syncthreads();

  const int base = wv * 128;          // wave-owned 128-element chunk
  const int i0 = base + lane;         // slot 0 element index
  const int i1 = base + lane + 64;    // slot 1 element index

  // Phase 1: levels len=2..128 fully in registers (shfl_xor; race-free)
  {
    uint64_t v0 = sk[i0], v1 = sk[i1];
    #pragma unroll
    for (int len = 2; len <= 128; len <<= 1) {
      #pragma unroll
      for (int str = len >> 1; str > 0; str >>= 1) {
        if (str == 64) {
          bool up = ((i0 & len) == 0);
          uint64_t mn = (v0 < v1) ? v0 : v1;
          uint64_t mx = (v0 < v1) ? v1 : v0;
          v0 = up ? mn : mx; v1 = up ? mx : mn;
        } else {
          v0 = cex64(v0, i0, len, str, lane);
          v1 = cex64(v1, i1, len, str, lane);
        }
      }
    }
    sk[i0] = v0; sk[i1] = v1;
  }
  __syncthreads();

  // Phase 2: levels len=256..2048 — LDS passes for str>=128, register tail
  for (int len = 256; len <= CAND_CAP; len <<= 1) {
    for (int str = len >> 1; str >= 128; str >>= 1) {
      for (int i = tid; i < CAND_CAP; i += 1024) {
        int j = i ^ str;
        if (j > i) {
          bool up = ((i & len) == 0);
          uint64_t x = sk[i], y = sk[j];
          if ((x > y) == up) { sk[i] = y; sk[j] = x; }
        }
      }
      __syncthreads();
    }
    {
      uint64_t v0 = sk[i0], v1 = sk[i1];
      bool up = ((i0 & len) == 0);       // str=64: intra-thread pair
      uint64_t mn = (v0 < v1) ? v0 : v1;
      uint64_t mx = (v0 < v1) ? v1 : v0;
      v0 = up ? mn : mx; v1 = up ? mx : mn;
      #pragma unroll
      for (int str = 32; str > 0; str >>= 1) {
        v0 = cex64(v0, i0, len, str, lane);
        v1 = cex64(v1, i1, len, str, lane);
      }
      sk[i0] = v0; sk[i1] = v1;
    }
    __syncthreads();
  }

  // ---- decode entry `tid` (rank tid, descending) ----
  if (tid < KTOP) {
#pragma clang fp contract(off)
    int t = n*KTOP + tid;
    uint64_t key = sk[CAND_CAP-1-tid];
    uint32_t idx = ~(uint32_t)(key & 0xFFFFFFFFull);
    float s = __uint_as_float((uint32_t)(key >> 32));
    int a = idx % AANCH, pos = idx / AANCH;
    int w = pos % WDIM, h = pos / WDIM;
    float d[5], an[5];
    #pragma unroll
    for (int j = 0; j < 5; ++j)
      d[j] = breg[((n*(AANCH*5) + (a*5+j))*HDIM + h)*WDIM + w];
    #pragma unroll
    for (int j = 0; j < 5; ++j)
      an[j] = anch[((size_t)n*MTOT + idx)*5 + j];
    const float CLIP = 4.135166556742356f;           // log(1000/16)
    float dw = fminf(d[2], CLIP), dh = fminf(d[3], CLIP);
    float x  = d[0]*an[2] + an[0];
    float y  = d[1]*an[3] + an[1];
    float bw = expf(dw)*an[2];
    float bh = expf(dh)*an[3];
    float th = an[4] + d[4]*57.29577951308232f;      // 180/pi
    prop[t*5+0]=x; prop[t*5+1]=y; prop[t*5+2]=bw; prop[t*5+3]=bh; prop[t*5+4]=th;
    score[t] = s;
    validf[t] = (bw >= 4.0f && bh >= 4.0f) ? 1u : 0u;
    area[t] = bw*bh;
    float r = 0.5f*sqrtf(bw*bw + bh*bh);
    xyr[t] = make_float4(x, y, r, 0.0f);
    float ang = th * 0.017453292519943295f;          // pi/180
    float cs = cosf(ang), sn = sinf(ang);
    float hw2 = bw*0.5f, hh2 = bh*0.5f;
    const float sx[4] = {1.f,-1.f,-1.f,1.f};
    const float sy[4] = {1.f,1.f,-1.f,-1.f};
    #pragma unroll
    for (int k = 0; k < 4; ++k) {
      float dxk = sx[k]*hw2, dyk = sy[k]*hh2;
      float cx = (x + cs*dxk) - sn*dyk;
      float cy = (y + sn*dxk) + cs*dyk;
      corn[t*8 + k*2 + 0] = cx;
      corn[t*8 + k*2 + 1] = cy;
    }
  }
}

// ---------------- Sutherland-Hodgman, register-resident ----------------
__device__ __forceinline__ float quad_inter_area(const float* __restrict__ ca,
                                                 const float* __restrict__ cb) {
#pragma clang fp contract(off)
  float px[8], py[8];
  int n = 4;
  #pragma unroll
  for (int i = 0; i < 4; ++i) { px[i] = ca[2*i]; py[i] = ca[2*i+1]; }
  #pragma unroll
  for (int i = 4; i < 8; ++i) { px[i] = 0.0f; py[i] = 0.0f; }
  #pragma unroll
  for (int e = 0; e < 4; ++e) {
    float p1x = cb[2*e], p1y = cb[2*e+1];
    int e2 = (e+1)&3;
    float dx = cb[2*e2] - p1x, dy = cb[2*e2+1] - p1y;
    float sd[8];
    #pragma unroll
    for (int i = 0; i < 8; ++i)
      sd[i] = dx*(py[i]-p1y) - dy*(px[i]-p1x);   // only i<n consumed
    float qx[8], qy[8];
    #pragma unroll
    for (int i = 0; i < 8; ++i) { qx[i] = 0.0f; qy[i] = 0.0f; }
    int m = 0;
    #pragma unroll
    for (int i = 0; i < 8; ++i) {
      if (i < n) {
        bool wrap = !(i+1 < n);
        float sdi = sd[i];
        float sdn = wrap ? sd[0] : sd[(i+1)&7];
        float pnx = wrap ? px[0] : px[(i+1)&7];
        float pny = wrap ? py[0] : py[(i+1)&7];
        bool ini = sdi >= 0.0f, inn = sdn >= 0.0f;
        if (ini) {
          float vx = px[i], vy = py[i];
          #pragma unroll
          for (int k = 0; k < 8; ++k) if (m == k) { qx[k] = vx; qy[k] = vy; }
          ++m;
        }
        if (ini != inn) {
          float den = sdi - sdn;
          float dd = (fabsf(den) < 1e-12f) ? 1e-12f : den;
          float tt = sdi/dd;
          float vx = px[i] + tt*(pnx - px[i]);
          float vy = py[i] + tt*(pny - py[i]);
          #pragma unroll
          for (int k = 0; k < 8; ++k) if (m == k) { qx[k] = vx; qy[k] = vy; }
          ++m;
        }
      }
    }
    n = m;
    #pragma unroll
    for (int i = 0; i < 8; ++i) { px[i] = qx[i]; py[i] = qy[i]; }
  }
  float ssum = 0.0f;
  #pragma unroll
  for (int i = 0; i < 8; ++i) {
    if (i < n) {
      bool wrap = !(i+1 < n);
      float pnx = wrap ? px[0] : px[(i+1)&7];
      float pny = wrap ? py[0] : py[(i+1)&7];
      ssum += px[i]*pny - pnx*py[i];
    }
  }
  return 0.5f*fabsf(ssum);
}

// ---------------- fused circle-test + clip + last-block Jacobi NMS ----------------
__global__ __launch_bounds__(256) void k_iou(const float4* __restrict__ xyr,
                                             const float* __restrict__ corn,
                                             const float* __restrict__ area,
                                             uint64_t* __restrict__ maskT,
                                             uint32_t* done_iou,
                                             const uint32_t* __restrict__ validf,
                                             const float* __restrict__ prop,
                                             const float* __restrict__ score,
                                             float* __restrict__ out) {
  __shared__ float4 sxyr[KTOP];            // 16000 B
  __shared__ uint32_t q[QCAP];             // 16384 B
  __shared__ uint32_t qcnt;
  __shared__ uint32_t mrow32[IOU_WPB*2];
  __shared__ float ca[IOU_ROWS*8];
  __shared__ float aa[IOU_ROWS];
  __shared__ uint32_t lastf;
  __shared__ uint64_t kwA[NWORDS];
  __shared__ uint64_t vwv[NWORDS];
  __shared__ int changed;
  int n = blockIdx.x / IOU_BPB;
  int wbase = (blockIdx.x % IOU_BPB) * IOU_WPB;
  int i0 = wbase >> 4;                     // first owned i-row
  int tid = threadIdx.x, wv = tid >> 6, lane = tid & 63;
  // stage
  for (int t = tid; t < KTOP; t += 256) sxyr[t] = xyr[n*KTOP + t];
  if (tid == 0) qcnt = 0;
  if (tid < IOU_WPB*2) mrow32[tid] = 0;
  if (tid >= 128 && tid < 128 + IOU_ROWS*8)
    ca[tid-128] = corn[(size_t)(n*KTOP + i0)*8 + (tid-128)];
  if (tid >= 160 && tid < 160 + IOU_ROWS)
    aa[tid-160] = area[n*KTOP + i0 + (tid-160)];
  __syncthreads();
  // scan: 16 words per wave, all LDS reads
  for (int w = wv; w < IOU_WPB; w += 4) {
    int word = wbase + w;
    int i = word >> 4;
    int jb = word & 15;
    if (jb*64 + 63 <= i) continue;
    int j = jb*64 + lane;
    bool hit = false;
    if (j > i && j < KTOP) {
      float4 a = sxyr[i];
      float4 b = sxyr[j];
      float dx = a.x - b.x, dy = a.y - b.y;
      float rs = a.z + b.z;
      hit = (dx*dx + dy*dy) <= rs*rs*1.0001f;
    }
    unsigned long long bal = __ballot(hit);
    if (!bal) continue;
    int tot = __popcll(bal);
    int leader = __ffsll(bal) - 1;
    uint32_t base = 0;
    if (lane == leader) base = atomicAdd(&qcnt, (uint32_t)tot);
    base = __shfl(base, leader);
    if (hit) {
      int pos = __popcll(bal & ((1ull << lane) - 1ull));
      q[base + pos] = ((uint32_t)i << 10) | (uint32_t)j;
    }
  }
  __syncthreads();
  uint32_t cntq = qcnt;
  for (uint32_t t = tid; t < cntq; t += 256) {
    uint32_t code = q[t];
    int i = code >> 10, j = code & 1023;
    int bj = n*KTOP + j;
    float inter = quad_inter_area(&ca[(i - i0)*8], &corn[(size_t)bj*8]);
    float uni = (aa[i - i0] + area[bj]) - inter;
    if (inter / fmaxf(uni, 1e-8f) > NMS_TH)
      atomicOr(&mrow32[((i - i0)*NWORDS + (j >> 6))*2 + ((j >> 5) & 1)],
               1u << (j & 31));
  }
  __syncthreads();
  // store transposed mask (disjoint cells, full overwrite)
  uint64_t* MT = &maskT[(size_t)n*NWORDS*KTOP];
  for (int t = tid; t < IOU_WPB; t += 256) {
    int r = t >> 4, l = t & 15;
    MT[(size_t)l*KTOP + i0 + r] =
      (uint64_t)mrow32[(r*NWORDS + l)*2] | ((uint64_t)mrow32[(r*NWORDS + l)*2 + 1] << 32);
  }
  // ---- last-block-per-batch: Jacobi fixpoint NMS (reads mask from L2/L3) ----
  __threadfence();                                   // release mask stores
  if (tid == 0) lastf = (atomicAdd(&done_iou[n], 1u) == IOU_BPB-1) ? 1u : 0u;
  __syncthreads();
  if (!lastf) return;
  __threadfence();                                   // acquire (invalidate stale)

  if (wv == 0) {
    #pragma unroll
    for (int w = 0; w < NWORDS; ++w) {
      int k = w*64 + lane;
      uint32_t v = (k < KTOP) ? validf[n*KTOP + k] : 0u;
      unsigned long long bm = __ballot(v != 0u);
      if (lane == 0) { vwv[w] = (uint64_t)bm; kwA[w] = (uint64_t)bm; }
    }
  }
  __syncthreads();

  int l0 = wv*4;    // this wave owns column-words l0..l0+3
  for (int it = 0; it < 256; ++it) {
    if (tid == 0) changed = 0;
    uint64_t a0 = 0, a1 = 0, a2 = 0, a3 = 0;
    #pragma unroll
    for (int k = 0; k < NWORDS; ++k) {
      int row = k*64 + lane;
      uint64_t bitm = (uint64_t)0 - ((kwA[k] >> lane) & 1ull);
      if (row < KTOP) {
        a0 |= MT[(size_t)(l0+0)*KTOP + row] & bitm;
        a1 |= MT[(size_t)(l0+1)*KTOP + row] & bitm;
        a2 |= MT[(size_t)(l0+2)*KTOP + row] & bitm;
        a3 |= MT[(size_t)(l0+3)*KTOP + row] & bitm;
      }
    }
    #pragma unroll
    for (int s = 1; s < 64; s <<= 1) {
      a0 |= __shfl_xor(a0, s);
      a1 |= __shfl_xor(a1, s);
      a2 |= __shfl_xor(a2, s);
      a3 |= __shfl_xor(a3, s);
    }
    __syncthreads();                   // all kwA reads done; changed reset visible
    if (lane == 0) {
      uint64_t n0 = vwv[l0+0] & ~a0; if (n0 != kwA[l0+0]) changed = 1; kwA[l0+0] = n0;
      uint64_t n1 = vwv[l0+1] & ~a1; if (n1 != kwA[l0+1]) changed = 1; kwA[l0+1] = n1;
      uint64_t n2 = vwv[l0+2] & ~a2; if (n2 != kwA[l0+2]) changed = 1; kwA[l0+2] = n2;
      uint64_t n3 = vwv[l0+3] & ~a3; if (n3 != kwA[l0+3]) changed = 1; kwA[l0+3] = n3;
    }
    __syncthreads();
    if (!changed) break;
  }

  // rank <= POSTN trim (thread 0), then all threads write output
  if (tid == 0) {
    int prev = 0;
    #pragma unroll
    for (int t = 0; t < NWORDS; ++t) {
      uint64_t wrd = kwA[t];
      int pc = __popcll(wrd);
      if (prev >= POSTN) wrd = 0;
      else if (prev + pc > POSTN) {
        int allow = POSTN - prev;
        while (__popcll(wrd) > allow) wrd &= ~(1ull << (63 - __clzll(wrd)));
      }
      prev += __popcll(wrd);
      kwA[t] = wrd;
    }
  }
  __syncthreads();
  for (int k = tid; k < KTOP; k += 256) {
    bool bb = (kwA[k>>6] >> (k&63)) & 1ull;
    float f = bb ? 1.0f : 0.0f;
    int t = n*KTOP + k;
    #pragma unroll
    for (int c = 0; c < 5; ++c) out[t*6 + c] = prop[t*5 + c] * f;
    out[t*6 + 5] = score[t] * f;
  }
}

extern "C" void kernel_launch(void* const* d_in, const int* in_sizes, int n_in,
                              void* d_out, int out_size, void* d_ws, size_t ws_size,
                              hipStream_t stream) {
  const float* obj  = (const float*)d_in[0];
  const float* breg = (const float*)d_in[1];
  const float* anch = (const float*)d_in[2];
  float* out = (float*)d_out;
  char* ws = (char*)d_ws;

  uint32_t* hist   = (uint32_t*)(ws + OFF_HIST);
  uint32_t* cnt    = (uint32_t*)(ws + OFF_CNT);
  uint32_t* thr    = (uint32_t*)(ws + OFF_THR);
  uint32_t* done_h = (uint32_t*)(ws + OFF_THR + 64);
  uint32_t* done_i = (uint32_t*)(ws + OFF_THR + 128);
  uint64_t* cand   = (uint64_t*)(ws + OFF_CAND);
  float*    prop   = (float*)(ws + OFF_PROP);
  float*    score  = (float*)(ws + OFF_SCORE);
  float*    corn   = (float*)(ws + OFF_CORN);
  float*    area   = (float*)(ws + OFF_AREA);
  uint32_t* validf = (uint32_t*)(ws + OFF_VALID);
  float4*   xyr    = (float4*)(ws + OFF_XYR);
  uint64_t* maskT  = (uint64_t*)(ws + OFF_MASK);

  k_zero   <<<(ZERO_U4+255)/256, 256, 0, stream>>>((uint4*)ws);
  k_hist   <<<NBATCH*BPB, 256, 0, stream>>>(obj, hist, thr, done_h);
  k_compact<<<NBATCH*CBLK, 256, 0, stream>>>(obj, thr, cand, cnt);
  k_sortdec<<<NBATCH, 1024, 0, stream>>>(cand, cnt, breg, anch, prop, score, corn, area, xyr, validf);
  k_iou    <<<NBATCH*IOU_BPB, 256, 0, stream>>>(xyr, corn, area, maskT, done_i, validf, prop, score, out);
}

// Round 18
// 135.693 us; speedup vs baseline: 1.5712x; 1.5712x over previous
//
#include <hip/hip_runtime.h>
#include <stdint.h>

// RPN rotated-NMS post-processor, MI355X. Round 18: partial revert of r17 —
// keep hist+thresh fusion and k_zero, restore separate LDS-staged Jacobi
// k_nms (the r17 fused tail lost mask LDS locality: 112us -> this restores).

#define NBATCH 4
#define AANCH 15
#define HDIM 200
#define WDIM 200
#define MTOT (AANCH*HDIM*WDIM)   // 600000
#define KTOP 1000
#define POSTN 300
#define NBINS 16384
#define CAND_CAP 2048
#define NWORDS 16                // ceil(1000/64)
#define NMS_TH 0.7f
#define BPB 75                   // blocks per batch for hist
#define CHUNK (MTOT/BPB)         // 8000
#define IOU_ROWS 4               // i-rows per iou block
#define IOU_BPB 250              // iou blocks per batch
#define IOU_WPB (IOU_ROWS*NWORDS) // 64 mask words per iou block
#define QCAP 4096                // provable max survivors (4 rows x <=1000 j)
#define NQ4 (MTOT/4)             // 150000 float4 per batch
#define CBLK ((NQ4+255)/256)     // 586 compact blocks per batch

// ---------------- ws layout ----------------
constexpr size_t OFF_HIST = 0;
constexpr size_t SZ_HIST  = (size_t)NBATCH*NBINS*4;                 // 262144
constexpr size_t OFF_CNT  = OFF_HIST + SZ_HIST;
constexpr size_t OFF_THR  = OFF_CNT + 256;   // thr[4] @ +0, done_hist[4] @ +64
constexpr size_t OFF_CAND = OFF_THR + 256;                          // 262656 B zeroed
constexpr size_t OFF_PROP = OFF_CAND + (size_t)NBATCH*CAND_CAP*8;
constexpr size_t OFF_SCORE= OFF_PROP + (size_t)NBATCH*KTOP*5*4;
constexpr size_t OFF_CORN = OFF_SCORE+ (size_t)NBATCH*KTOP*4;
constexpr size_t OFF_AREA = OFF_CORN + (size_t)NBATCH*KTOP*8*4;
constexpr size_t OFF_VALID= OFF_AREA + (size_t)NBATCH*KTOP*4;
constexpr size_t OFF_XYR  = OFF_VALID+ (size_t)NBATCH*KTOP*4;
constexpr size_t OFF_MASK = OFF_XYR  + (size_t)NBATCH*KTOP*16;      // maskT [n][l][row]

constexpr int ZERO_U4 = (int)(OFF_CAND / 16);   // 16416 uint4 (hist+cnt+thr+done)

__device__ __forceinline__ float sigmoid_ref(float x) {
  return 1.0f / (1.0f + expf(-x));
}

// ---------------- zero scratch header ----------------
__global__ __launch_bounds__(256) void k_zero(uint4* __restrict__ p) {
  int t = blockIdx.x*256 + threadIdx.x;
  if (t < ZERO_U4) p[t] = make_uint4(0u,0u,0u,0u);
}

// ---------------- histogram (LDS-privatized) + last-block threshold scan ----------------
__global__ __launch_bounds__(256) void k_hist(const float* __restrict__ obj,
                                              uint32_t* hist,
                                              uint32_t* thr,
                                              uint32_t* done_hist) {
  __shared__ uint32_t h[NBINS];
  __shared__ uint32_t ps[256];
  __shared__ uint32_t lastf;
  for (int i = threadIdx.x; i < NBINS; i += 256) h[i] = 0;
  __syncthreads();
  int n = blockIdx.x / BPB, c = blockIdx.x % BPB;
  int tid = threadIdx.x;
  const float4* p = (const float4*)(obj + (size_t)n*MTOT + (size_t)c*CHUNK);
  const int nq = CHUNK/4;
  for (int q = tid; q < nq; q += 256) {
    float4 v = p[q];
    #pragma unroll
    for (int k = 0; k < 4; ++k) {
      float x = (&v.x)[k];
      uint32_t bits = __float_as_uint(sigmoid_ref(x));
      uint32_t bin = bits >> 16; if (bin > NBINS-1) bin = NBINS-1;
      atomicAdd(&h[bin], 1u);
    }
  }
  __syncthreads();
  uint32_t* hb = &hist[n*NBINS];
  for (int i = tid; i < NBINS; i += 256) {
    uint32_t v = h[i];
    if (v) atomicAdd(&hb[i], v);
  }
  // ---- last-block-per-batch threshold scan ----
  __threadfence();
  if (tid == 0) lastf = (atomicAdd(&done_hist[n], 1u) == BPB-1) ? 1u : 0u;
  __syncthreads();
  if (!lastf) return;
  __threadfence();
  uint32_t s = 0;
  for (int b = tid*64; b < tid*64+64; ++b) s += atomicAdd(&hb[b], 0u);
  ps[tid] = s;
  __syncthreads();
  if (tid == 0) {
    uint32_t cum = 0; int cidx = -1;
    for (int cc = 255; cc >= 0; --cc) {
      if (cum + ps[cc] >= KTOP) { cidx = cc; break; }
      cum += ps[cc];
    }
    if (cidx < 0) { thr[n] = 0u; return; }
    int b = cidx*64+63;
    for (; b >= cidx*64; --b) { cum += atomicAdd(&hb[b], 0u); if (cum >= KTOP) break; }
    thr[n] = (uint32_t)(b < 0 ? 0 : b);
  }
}

// ---------------- compact: float4 loads + block-aggregated atomic ----------------
__global__ __launch_bounds__(256) void k_compact(const float* __restrict__ obj,
                                                 const uint32_t* __restrict__ thr,
                                                 uint64_t* __restrict__ cand,
                                                 uint32_t* __restrict__ cnt) {
  __shared__ uint32_t wtot[4];
  __shared__ uint32_t gbase;
  int n = blockIdx.x / CBLK, c = blockIdx.x % CBLK;
  int tid = threadIdx.x, wv = tid >> 6, lane = tid & 63;
  int q = c*256 + tid;                 // float4 index within batch
  uint32_t th = thr[n];
  bool hit0=false, hit1=false, hit2=false, hit3=false;
  uint32_t bits[4], fidx[4];
  if (q < NQ4) {
    float4 v = ((const float4*)(obj + (size_t)n*MTOT))[q];
    #pragma unroll
    for (int k = 0; k < 4; ++k) {
      float x = (&v.x)[k];
      uint32_t b = __float_as_uint(sigmoid_ref(x));
      uint32_t bin = b >> 16; if (bin > NBINS-1) bin = NBINS-1;
      bits[k] = b;
      int rem = q*4 + k;               // element index within batch
      int hw = rem % (HDIM*WDIM);
      int a  = rem / (HDIM*WDIM);
      fidx[k] = (uint32_t)(hw*AANCH + a);
      bool hk = (bin >= th);
      if (k == 0) hit0 = hk; else if (k == 1) hit1 = hk;
      else if (k == 2) hit2 = hk; else hit3 = hk;
    }
  }
  unsigned long long m0 = __ballot(hit0);
  unsigned long long m1 = __ballot(hit1);
  unsigned long long m2 = __ballot(hit2);
  unsigned long long m3 = __ballot(hit3);
  if (lane == 0)
    wtot[wv] = (uint32_t)(__popcll(m0)+__popcll(m1)+__popcll(m2)+__popcll(m3));
  __syncthreads();
  if (tid == 0) {
    uint32_t t0 = wtot[0], t1 = wtot[1], t2 = wtot[2], t3 = wtot[3];
    uint32_t tot = t0+t1+t2+t3;
    gbase = tot ? atomicAdd(&cnt[n], tot) : 0u;
    wtot[0] = 0; wtot[1] = t0; wtot[2] = t0+t1; wtot[3] = t0+t1+t2;
  }
  __syncthreads();
  uint32_t base = gbase + wtot[wv];
  unsigned long long below = (1ull << lane) - 1ull;
  uint32_t off = 0;
  bool hits[4] = {hit0, hit1, hit2, hit3};
  unsigned long long ms[4] = {m0, m1, m2, m3};
  #pragma unroll
  for (int k = 0; k < 4; ++k) {
    if (hits[k]) {
      uint32_t p = base + off + (uint32_t)__popcll(ms[k] & below);
      if (p < CAND_CAP)
        cand[(size_t)n*CAND_CAP + p] = ((uint64_t)bits[k] << 32) | (uint32_t)(~fidx[k]);
    }
    off += (uint32_t)__popcll(ms[k]);
  }
}

// ---------------- register compare-exchange for wave-local bitonic ----------------
__device__ __forceinline__ uint64_t cex64(uint64_t v, int i, int len, int str, int lane) {
  uint64_t p = __shfl_xor(v, str);
  bool up = ((i & len) == 0);
  bool lower = ((lane & str) == 0);
  uint64_t mn = (v < p) ? v : p;
  uint64_t mx = (v < p) ? p : v;
  return (up == lower) ? mn : mx;
}

// ---------------- hybrid bitonic sort (register wave-local phases) + decode ----------------
__global__ __launch_bounds__(1024) void k_sortdec(const uint64_t* __restrict__ cand,
                                                  const uint32_t* __restrict__ cnt,
                                                  const float* __restrict__ breg,
                                                  const float* __restrict__ anch,
                                                  float* __restrict__ prop,
                                                  float* __restrict__ score,
                                                  float* __restrict__ corn,
                                                  float* __restrict__ area,
                                                  float4* __restrict__ xyr,
                                                  uint32_t* __restrict__ validf) {
  __shared__ uint64_t sk[CAND_CAP];
  int n = blockIdx.x, tid = threadIdx.x;
  int lane = tid & 63, wv = tid >> 6;
  uint32_t c = cnt[n]; if (c > CAND_CAP) c = CAND_CAP;
  for (int i = tid; i < CAND_CAP; i += 1024)
    sk[i] = (i < (int)c) ? cand[(size_t)n*CAND_CAP + i] : 0ull;
  __syncthreads();

  const int base = wv * 128;          // wave-owned 128-element chunk
  const int i0 = base + lane;         // slot 0 element index
  const int i1 = base + lane + 64;    // slot 1 element index

  // Phase 1: levels len=2..128 fully in registers (shfl_xor; race-free)
  {
    uint64_t v0 = sk[i0], v1 = sk[i1];
    #pragma unroll
    for (int len = 2; len <= 128; len <<= 1) {
      #pragma unroll
      for (int str = len >> 1; str > 0; str >>= 1) {
        if (str == 64) {
          bool up = ((i0 & len) == 0);
          uint64_t mn = (v0 < v1) ? v0 : v1;
          uint64_t mx = (v0 < v1) ? v1 : v0;
          v0 = up ? mn : mx; v1 = up ? mx : mn;
        } else {
          v0 = cex64(v0, i0, len, str, lane);
          v1 = cex64(v1, i1, len, str, lane);
        }
      }
    }
    sk[i0] = v0; sk[i1] = v1;
  }
  __syncthreads();

  // Phase 2: levels len=256..2048 — LDS passes for str>=128, register tail
  for (int len = 256; len <= CAND_CAP; len <<= 1) {
    for (int str = len >> 1; str >= 128; str >>= 1) {
      for (int i = tid; i < CAND_CAP; i += 1024) {
        int j = i ^ str;
        if (j > i) {
          bool up = ((i & len) == 0);
          uint64_t x = sk[i], y = sk[j];
          if ((x > y) == up) { sk[i] = y; sk[j] = x; }
        }
      }
      __syncthreads();
    }
    {
      uint64_t v0 = sk[i0], v1 = sk[i1];
      bool up = ((i0 & len) == 0);       // str=64: intra-thread pair
      uint64_t mn = (v0 < v1) ? v0 : v1;
      uint64_t mx = (v0 < v1) ? v1 : v0;
      v0 = up ? mn : mx; v1 = up ? mx : mn;
      #pragma unroll
      for (int str = 32; str > 0; str >>= 1) {
        v0 = cex64(v0, i0, len, str, lane);
        v1 = cex64(v1, i1, len, str, lane);
      }
      sk[i0] = v0; sk[i1] = v1;
    }
    __syncthreads();
  }

  // ---- decode entry `tid` (rank tid, descending) ----
  if (tid < KTOP) {
#pragma clang fp contract(off)
    int t = n*KTOP + tid;
    uint64_t key = sk[CAND_CAP-1-tid];
    uint32_t idx = ~(uint32_t)(key & 0xFFFFFFFFull);
    float s = __uint_as_float((uint32_t)(key >> 32));
    int a = idx % AANCH, pos = idx / AANCH;
    int w = pos % WDIM, h = pos / WDIM;
    float d[5], an[5];
    #pragma unroll
    for (int j = 0; j < 5; ++j)
      d[j] = breg[((n*(AANCH*5) + (a*5+j))*HDIM + h)*WDIM + w];
    #pragma unroll
    for (int j = 0; j < 5; ++j)
      an[j] = anch[((size_t)n*MTOT + idx)*5 + j];
    const float CLIP = 4.135166556742356f;           // log(1000/16)
    float dw = fminf(d[2], CLIP), dh = fminf(d[3], CLIP);
    float x  = d[0]*an[2] + an[0];
    float y  = d[1]*an[3] + an[1];
    float bw = expf(dw)*an[2];
    float bh = expf(dh)*an[3];
    float th = an[4] + d[4]*57.29577951308232f;      // 180/pi
    prop[t*5+0]=x; prop[t*5+1]=y; prop[t*5+2]=bw; prop[t*5+3]=bh; prop[t*5+4]=th;
    score[t] = s;
    validf[t] = (bw >= 4.0f && bh >= 4.0f) ? 1u : 0u;
    area[t] = bw*bh;
    float r = 0.5f*sqrtf(bw*bw + bh*bh);
    xyr[t] = make_float4(x, y, r, 0.0f);
    float ang = th * 0.017453292519943295f;          // pi/180
    float cs = cosf(ang), sn = sinf(ang);
    float hw2 = bw*0.5f, hh2 = bh*0.5f;
    const float sx[4] = {1.f,-1.f,-1.f,1.f};
    const float sy[4] = {1.f,1.f,-1.f,-1.f};
    #pragma unroll
    for (int k = 0; k < 4; ++k) {
      float dxk = sx[k]*hw2, dyk = sy[k]*hh2;
      float cx = (x + cs*dxk) - sn*dyk;
      float cy = (y + sn*dxk) + cs*dyk;
      corn[t*8 + k*2 + 0] = cx;
      corn[t*8 + k*2 + 1] = cy;
    }
  }
}

// ---------------- Sutherland-Hodgman, register-resident ----------------
__device__ __forceinline__ float quad_inter_area(const float* __restrict__ ca,
                                                 const float* __restrict__ cb) {
#pragma clang fp contract(off)
  float px[8], py[8];
  int n = 4;
  #pragma unroll
  for (int i = 0; i < 4; ++i) { px[i] = ca[2*i]; py[i] = ca[2*i+1]; }
  #pragma unroll
  for (int i = 4; i < 8; ++i) { px[i] = 0.0f; py[i] = 0.0f; }
  #pragma unroll
  for (int e = 0; e < 4; ++e) {
    float p1x = cb[2*e], p1y = cb[2*e+1];
    int e2 = (e+1)&3;
    float dx = cb[2*e2] - p1x, dy = cb[2*e2+1] - p1y;
    float sd[8];
    #pragma unroll
    for (int i = 0; i < 8; ++i)
      sd[i] = dx*(py[i]-p1y) - dy*(px[i]-p1x);   // only i<n consumed
    float qx[8], qy[8];
    #pragma unroll
    for (int i = 0; i < 8; ++i) { qx[i] = 0.0f; qy[i] = 0.0f; }
    int m = 0;
    #pragma unroll
    for (int i = 0; i < 8; ++i) {
      if (i < n) {
        bool wrap = !(i+1 < n);
        float sdi = sd[i];
        float sdn = wrap ? sd[0] : sd[(i+1)&7];
        float pnx = wrap ? px[0] : px[(i+1)&7];
        float pny = wrap ? py[0] : py[(i+1)&7];
        bool ini = sdi >= 0.0f, inn = sdn >= 0.0f;
        if (ini) {
          float vx = px[i], vy = py[i];
          #pragma unroll
          for (int k = 0; k < 8; ++k) if (m == k) { qx[k] = vx; qy[k] = vy; }
          ++m;
        }
        if (ini != inn) {
          float den = sdi - sdn;
          float dd = (fabsf(den) < 1e-12f) ? 1e-12f : den;
          float tt = sdi/dd;
          float vx = px[i] + tt*(pnx - px[i]);
          float vy = py[i] + tt*(pny - py[i]);
          #pragma unroll
          for (int k = 0; k < 8; ++k) if (m == k) { qx[k] = vx; qy[k] = vy; }
          ++m;
        }
      }
    }
    n = m;
    #pragma unroll
    for (int i = 0; i < 8; ++i) { px[i] = qx[i]; py[i] = qy[i]; }
  }
  float ssum = 0.0f;
  #pragma unroll
  for (int i = 0; i < 8; ++i) {
    if (i < n) {
      bool wrap = !(i+1 < n);
      float pnx = wrap ? px[0] : px[(i+1)&7];
      float pny = wrap ? py[0] : py[(i+1)&7];
      ssum += px[i]*pny - pnx*py[i];
    }
  }
  return 0.5f*fabsf(ssum);
}

// ---------------- fused circle-test + clip; xyr staged in LDS; 4 rows/block ----------------
__global__ __launch_bounds__(256) void k_iou(const float4* __restrict__ xyr,
                                             const float* __restrict__ corn,
                                             const float* __restrict__ area,
                                             uint64_t* __restrict__ maskT) {
  __shared__ float4 sxyr[KTOP];            // 16000 B, this batch's boxes
  __shared__ uint32_t q[QCAP];             // 16384 B
  __shared__ uint32_t qcnt;
  __shared__ uint32_t mrow32[IOU_WPB*2];   // 4 rows x 16 words x 2 halves
  __shared__ float ca[IOU_ROWS*8];         // own rows' corners
  __shared__ float aa[IOU_ROWS];
  int n = blockIdx.x / IOU_BPB;
  int wbase = (blockIdx.x % IOU_BPB) * IOU_WPB;
  int i0 = wbase >> 4;                     // first owned i-row
  int tid = threadIdx.x, wv = tid >> 6, lane = tid & 63;
  // stage
  for (int t = tid; t < KTOP; t += 256) sxyr[t] = xyr[n*KTOP + t];
  if (tid == 0) qcnt = 0;
  if (tid < IOU_WPB*2) mrow32[tid] = 0;
  if (tid >= 128 && tid < 128 + IOU_ROWS*8)
    ca[tid-128] = corn[(size_t)(n*KTOP + i0)*8 + (tid-128)];
  if (tid >= 160 && tid < 160 + IOU_ROWS)
    aa[tid-160] = area[n*KTOP + i0 + (tid-160)];
  __syncthreads();
  // scan: 16 words per wave, all LDS reads
  for (int w = wv; w < IOU_WPB; w += 4) {
    int word = wbase + w;
    int i = word >> 4;               // word / NWORDS
    int jb = word & 15;              // word % NWORDS
    if (jb*64 + 63 <= i) continue;   // no j > i in this word
    int j = jb*64 + lane;
    bool hit = false;
    if (j > i && j < KTOP) {
      float4 a = sxyr[i];            // wave-uniform LDS broadcast
      float4 b = sxyr[j];
      float dx = a.x - b.x, dy = a.y - b.y;
      float rs = a.z + b.z;
      hit = (dx*dx + dy*dy) <= rs*rs*1.0001f;
    }
    unsigned long long bal = __ballot(hit);
    if (!bal) continue;
    int tot = __popcll(bal);
    int leader = __ffsll(bal) - 1;
    uint32_t base = 0;
    if (lane == leader) base = atomicAdd(&qcnt, (uint32_t)tot);
    base = __shfl(base, leader);
    if (hit) {
      int pos = __popcll(bal & ((1ull << lane) - 1ull));
      q[base + pos] = ((uint32_t)i << 10) | (uint32_t)j;
    }
  }
  __syncthreads();
  uint32_t cnt = qcnt;
  for (uint32_t t = tid; t < cnt; t += 256) {
    uint32_t code = q[t];
    int i = code >> 10, j = code & 1023;
    int bj = n*KTOP + j;
    float inter = quad_inter_area(&ca[(i - i0)*8], &corn[(size_t)bj*8]);
    float uni = (aa[i - i0] + area[bj]) - inter;
    if (inter / fmaxf(uni, 1e-8f) > NMS_TH)
      atomicOr(&mrow32[((i - i0)*NWORDS + (j >> 6))*2 + ((j >> 5) & 1)],
               1u << (j & 31));
  }
  __syncthreads();
  // store transposed: maskT[n][l][row] (disjoint cells, full overwrite)
  uint64_t* dstT = &maskT[(size_t)n*NWORDS*KTOP];
  for (int t = tid; t < IOU_WPB; t += 256) {
    int r = t >> 4, l = t & 15;
    dstT[(size_t)l*KTOP + i0 + r] =
      (uint64_t)mrow32[(r*NWORDS + l)*2] | ((uint64_t)mrow32[(r*NWORDS + l)*2 + 1] << 32);
  }
}

// ---------------- greedy NMS via exact Jacobi fixpoint iteration ----------------
__global__ __launch_bounds__(1024) void k_nms(const uint32_t* __restrict__ validf,
                                              const uint64_t* __restrict__ maskT,
                                              const float* __restrict__ prop,
                                              const float* __restrict__ score,
                                              float* __restrict__ out) {
  __shared__ uint64_t sm[NWORDS*KTOP];   // 128000 B: sm[l*KTOP+row]
  __shared__ uint64_t kwA[NWORDS];       // current alive words
  __shared__ uint64_t vw[NWORDS];        // valid words (constant)
  __shared__ int changed;
  int n = blockIdx.x;
  int tid = threadIdx.x, wv = tid >> 6, lane = tid & 63;
  const uint64_t* MT = &maskT[(size_t)n*NWORDS*KTOP];
  for (int g = tid; g < NWORDS*KTOP; g += 1024) sm[g] = MT[g];
  if (wv == 0) {
    #pragma unroll
    for (int w = 0; w < NWORDS; ++w) {
      int k = w*64 + lane;
      uint32_t v = (k < KTOP) ? validf[n*KTOP + k] : 0u;
      unsigned long long bm = __ballot(v != 0u);
      if (lane == 0) { vw[w] = (uint64_t)bm; kwA[w] = (uint64_t)bm; }
    }
  }
  __syncthreads();

  int l = wv;   // 16 waves <-> 16 words
  for (int it = 0; it < 1024; ++it) {
    if (tid == 0) changed = 0;
    uint64_t acc = 0;
    #pragma unroll
    for (int k = 0; k < NWORDS; ++k) {
      int row = k*64 + lane;
      uint64_t aw = kwA[k];                       // LDS broadcast
      uint64_t mrow = (row < KTOP) ? sm[l*KTOP + row] : 0ull;
      uint64_t bit = (aw >> lane) & 1ull;
      acc |= mrow & ((uint64_t)0 - bit);
    }
    #pragma unroll
    for (int s = 1; s < 64; s <<= 1) acc |= __shfl_xor(acc, s);
    uint64_t newl = vw[l] & ~acc;
    __syncthreads();                              // all kwA reads done; changed reset visible
    if (lane == 0) {
      if (newl != kwA[l]) changed = 1;            // benign write race (all write 1)
      kwA[l] = newl;
    }
    __syncthreads();
    if (!changed) break;
  }

  if (tid == 0) {
    int prev = 0;
    #pragma unroll
    for (int t = 0; t < NWORDS; ++t) {
      uint64_t wrd = kwA[t];
      int pc = __popcll(wrd);
      if (prev >= POSTN) wrd = 0;
      else if (prev + pc > POSTN) {
        int allow = POSTN - prev;
        while (__popcll(wrd) > allow) wrd &= ~(1ull << (63 - __clzll(wrd)));
      }
      prev += __popcll(wrd);
      kwA[t] = wrd;
    }
  }
  __syncthreads();
  for (int k = tid; k < KTOP; k += 1024) {
    bool bb = (kwA[k>>6] >> (k&63)) & 1ull;
    float f = bb ? 1.0f : 0.0f;
    int t = n*KTOP + k;
    #pragma unroll
    for (int c = 0; c < 5; ++c) out[t*6 + c] = prop[t*5 + c] * f;
    out[t*6 + 5] = score[t] * f;
  }
}

extern "C" void kernel_launch(void* const* d_in, const int* in_sizes, int n_in,
                              void* d_out, int out_size, void* d_ws, size_t ws_size,
                              hipStream_t stream) {
  const float* obj  = (const float*)d_in[0];
  const float* breg = (const float*)d_in[1];
  const float* anch = (const float*)d_in[2];
  float* out = (float*)d_out;
  char* ws = (char*)d_ws;

  uint32_t* hist   = (uint32_t*)(ws + OFF_HIST);
  uint32_t* cnt    = (uint32_t*)(ws + OFF_CNT);
  uint32_t* thr    = (uint32_t*)(ws + OFF_THR);
  uint32_t* done_h = (uint32_t*)(ws + OFF_THR + 64);
  uint64_t* cand   = (uint64_t*)(ws + OFF_CAND);
  float*    prop   = (float*)(ws + OFF_PROP);
  float*    score  = (float*)(ws + OFF_SCORE);
  float*    corn   = (float*)(ws + OFF_CORN);
  float*    area   = (float*)(ws + OFF_AREA);
  uint32_t* validf = (uint32_t*)(ws + OFF_VALID);
  float4*   xyr    = (float4*)(ws + OFF_XYR);
  uint64_t* maskT  = (uint64_t*)(ws + OFF_MASK);

  k_zero   <<<(ZERO_U4+255)/256, 256, 0, stream>>>((uint4*)ws);
  k_hist   <<<NBATCH*BPB, 256, 0, stream>>>(obj, hist, thr, done_h);
  k_compact<<<NBATCH*CBLK, 256, 0, stream>>>(obj, thr, cand, cnt);
  k_sortdec<<<NBATCH, 1024, 0, stream>>>(cand, cnt, breg, anch, prop, score, corn, area, xyr, validf);
  k_iou    <<<NBATCH*IOU_BPB, 256, 0, stream>>>(xyr, corn, area, maskT);
  k_nms    <<<NBATCH, 1024, 0, stream>>>(validf, maskT, prop, score, out);
}

// Round 19
// 124.203 us; speedup vs baseline: 1.7166x; 1.0925x over previous
//
#include <hip/hip_runtime.h>
#include <stdint.h>

// RPN rotated-NMS post-processor, MI355X. Round 19: k_hist diet — 8192 bins
// (32KB LDS, 2x occupancy, halved init/flush), vectorized plain-load
// threshold tail (was 64 serial atomic reads). Rest identical to r18.

#define NBATCH 4
#define AANCH 15
#define HDIM 200
#define WDIM 200
#define MTOT (AANCH*HDIM*WDIM)   // 600000
#define KTOP 1000
#define POSTN 300
#define NBINS 8192               // sigmoid bits >> 17
#define CAND_CAP 2048
#define NWORDS 16                // ceil(1000/64)
#define NMS_TH 0.7f
#define BPB 75                   // blocks per batch for hist
#define CHUNK (MTOT/BPB)         // 8000
#define IOU_ROWS 4               // i-rows per iou block
#define IOU_BPB 250              // iou blocks per batch
#define IOU_WPB (IOU_ROWS*NWORDS) // 64 mask words per iou block
#define QCAP 4096                // provable max survivors (4 rows x <=1000 j)
#define NQ4 (MTOT/4)             // 150000 float4 per batch
#define CBLK ((NQ4+255)/256)     // 586 compact blocks per batch

// ---------------- ws layout ----------------
constexpr size_t OFF_HIST = 0;
constexpr size_t SZ_HIST  = (size_t)NBATCH*NBINS*4;                 // 131072
constexpr size_t OFF_CNT  = OFF_HIST + SZ_HIST;
constexpr size_t OFF_THR  = OFF_CNT + 256;   // thr[4] @ +0, done_hist[4] @ +64
constexpr size_t OFF_CAND = OFF_THR + 256;                          // zeroed prefix
constexpr size_t OFF_PROP = OFF_CAND + (size_t)NBATCH*CAND_CAP*8;
constexpr size_t OFF_SCORE= OFF_PROP + (size_t)NBATCH*KTOP*5*4;
constexpr size_t OFF_CORN = OFF_SCORE+ (size_t)NBATCH*KTOP*4;
constexpr size_t OFF_AREA = OFF_CORN + (size_t)NBATCH*KTOP*8*4;
constexpr size_t OFF_VALID= OFF_AREA + (size_t)NBATCH*KTOP*4;
constexpr size_t OFF_XYR  = OFF_VALID+ (size_t)NBATCH*KTOP*4;
constexpr size_t OFF_MASK = OFF_XYR  + (size_t)NBATCH*KTOP*16;      // maskT [n][l][row]

constexpr int ZERO_U4 = (int)(OFF_CAND / 16);

__device__ __forceinline__ float sigmoid_ref(float x) {
  return 1.0f / (1.0f + expf(-x));
}

// ---------------- zero scratch header ----------------
__global__ __launch_bounds__(256) void k_zero(uint4* __restrict__ p) {
  int t = blockIdx.x*256 + threadIdx.x;
  if (t < ZERO_U4) p[t] = make_uint4(0u,0u,0u,0u);
}

// ---------------- histogram (LDS-privatized) + last-block threshold scan ----------------
__global__ __launch_bounds__(256) void k_hist(const float* __restrict__ obj,
                                              uint32_t* hist,
                                              uint32_t* thr,
                                              uint32_t* done_hist) {
  __shared__ uint32_t h[NBINS];          // 32 KB
  __shared__ uint32_t ps[256];
  __shared__ uint32_t lastf;
  for (int i = threadIdx.x; i < NBINS; i += 256) h[i] = 0;
  __syncthreads();
  int n = blockIdx.x / BPB, c = blockIdx.x % BPB;
  int tid = threadIdx.x;
  const float4* p = (const float4*)(obj + (size_t)n*MTOT + (size_t)c*CHUNK);
  const int nq = CHUNK/4;
  for (int q = tid; q < nq; q += 256) {
    float4 v = p[q];
    #pragma unroll
    for (int k = 0; k < 4; ++k) {
      float x = (&v.x)[k];
      uint32_t bits = __float_as_uint(sigmoid_ref(x));
      uint32_t bin = bits >> 17; if (bin > NBINS-1) bin = NBINS-1;
      atomicAdd(&h[bin], 1u);
    }
  }
  __syncthreads();
  uint32_t* hb = &hist[n*NBINS];
  for (int i = tid; i < NBINS; i += 256) {
    uint32_t v = h[i];
    if (v) atomicAdd(&hb[i], v);
  }
  // ---- last-block-per-batch threshold scan ----
  __threadfence();                       // release hist atomics
  if (tid == 0) lastf = (atomicAdd(&done_hist[n], 1u) == BPB-1) ? 1u : 0u;
  __syncthreads();
  if (!lastf) return;
  __threadfence();                       // acquire
  // vectorized plain loads (coherent after fence+counter): 32 bins/thread
  uint32_t s = 0;
  {
    const uint4* hb4 = (const uint4*)hb;
    #pragma unroll
    for (int u = 0; u < 8; ++u) {
      uint4 v = hb4[tid*8 + u];
      s += v.x + v.y + v.z + v.w;
    }
  }
  ps[tid] = s;
  __syncthreads();
  if (tid == 0) {
    uint32_t cum = 0; int cidx = -1;
    for (int cc = 255; cc >= 0; --cc) {
      if (cum + ps[cc] >= KTOP) { cidx = cc; break; }
      cum += ps[cc];
    }
    if (cidx < 0) { thr[n] = 0u; return; }
    int b = cidx*32+31;
    for (; b >= cidx*32; --b) { cum += hb[b]; if (cum >= KTOP) break; }
    thr[n] = (uint32_t)(b < 0 ? 0 : b);
  }
}

// ---------------- compact: float4 loads + block-aggregated atomic ----------------
__global__ __launch_bounds__(256) void k_compact(const float* __restrict__ obj,
                                                 const uint32_t* __restrict__ thr,
                                                 uint64_t* __restrict__ cand,
                                                 uint32_t* __restrict__ cnt) {
  __shared__ uint32_t wtot[4];
  __shared__ uint32_t gbase;
  int n = blockIdx.x / CBLK, c = blockIdx.x % CBLK;
  int tid = threadIdx.x, wv = tid >> 6, lane = tid & 63;
  int q = c*256 + tid;                 // float4 index within batch
  uint32_t th = thr[n];
  bool hit0=false, hit1=false, hit2=false, hit3=false;
  uint32_t bits[4], fidx[4];
  if (q < NQ4) {
    float4 v = ((const float4*)(obj + (size_t)n*MTOT))[q];
    #pragma unroll
    for (int k = 0; k < 4; ++k) {
      float x = (&v.x)[k];
      uint32_t b = __float_as_uint(sigmoid_ref(x));
      uint32_t bin = b >> 17; if (bin > NBINS-1) bin = NBINS-1;
      bits[k] = b;
      int rem = q*4 + k;               // element index within batch
      int hw = rem % (HDIM*WDIM);
      int a  = rem / (HDIM*WDIM);
      fidx[k] = (uint32_t)(hw*AANCH + a);
      bool hk = (bin >= th);
      if (k == 0) hit0 = hk; else if (k == 1) hit1 = hk;
      else if (k == 2) hit2 = hk; else hit3 = hk;
    }
  }
  unsigned long long m0 = __ballot(hit0);
  unsigned long long m1 = __ballot(hit1);
  unsigned long long m2 = __ballot(hit2);
  unsigned long long m3 = __ballot(hit3);
  if (lane == 0)
    wtot[wv] = (uint32_t)(__popcll(m0)+__popcll(m1)+__popcll(m2)+__popcll(m3));
  __syncthreads();
  if (tid == 0) {
    uint32_t t0 = wtot[0], t1 = wtot[1], t2 = wtot[2], t3 = wtot[3];
    uint32_t tot = t0+t1+t2+t3;
    gbase = tot ? atomicAdd(&cnt[n], tot) : 0u;
    wtot[0] = 0; wtot[1] = t0; wtot[2] = t0+t1; wtot[3] = t0+t1+t2;
  }
  __syncthreads();
  uint32_t base = gbase + wtot[wv];
  unsigned long long below = (1ull << lane) - 1ull;
  uint32_t off = 0;
  bool hits[4] = {hit0, hit1, hit2, hit3};
  unsigned long long ms[4] = {m0, m1, m2, m3};
  #pragma unroll
  for (int k = 0; k < 4; ++k) {
    if (hits[k]) {
      uint32_t p = base + off + (uint32_t)__popcll(ms[k] & below);
      if (p < CAND_CAP)
        cand[(size_t)n*CAND_CAP + p] = ((uint64_t)bits[k] << 32) | (uint32_t)(~fidx[k]);
    }
    off += (uint32_t)__popcll(ms[k]);
  }
}

// ---------------- register compare-exchange for wave-local bitonic ----------------
__device__ __forceinline__ uint64_t cex64(uint64_t v, int i, int len, int str, int lane) {
  uint64_t p = __shfl_xor(v, str);
  bool up = ((i & len) == 0);
  bool lower = ((lane & str) == 0);
  uint64_t mn = (v < p) ? v : p;
  uint64_t mx = (v < p) ? p : v;
  return (up == lower) ? mn : mx;
}

// ---------------- hybrid bitonic sort (register wave-local phases) + decode ----------------
__global__ __launch_bounds__(1024) void k_sortdec(const uint64_t* __restrict__ cand,
                                                  const uint32_t* __restrict__ cnt,
                                                  const float* __restrict__ breg,
                                                  const float* __restrict__ anch,
                                                  float* __restrict__ prop,
                                                  float* __restrict__ score,
                                                  float* __restrict__ corn,
                                                  float* __restrict__ area,
                                                  float4* __restrict__ xyr,
                                                  uint32_t* __restrict__ validf) {
  __shared__ uint64_t sk[CAND_CAP];
  int n = blockIdx.x, tid = threadIdx.x;
  int lane = tid & 63, wv = tid >> 6;
  uint32_t c = cnt[n]; if (c > CAND_CAP) c = CAND_CAP;
  for (int i = tid; i < CAND_CAP; i += 1024)
    sk[i] = (i < (int)c) ? cand[(size_t)n*CAND_CAP + i] : 0ull;
  __syncthreads();

  const int base = wv * 128;          // wave-owned 128-element chunk
  const int i0 = base + lane;         // slot 0 element index
  const int i1 = base + lane + 64;    // slot 1 element index

  // Phase 1: levels len=2..128 fully in registers (shfl_xor; race-free)
  {
    uint64_t v0 = sk[i0], v1 = sk[i1];
    #pragma unroll
    for (int len = 2; len <= 128; len <<= 1) {
      #pragma unroll
      for (int str = len >> 1; str > 0; str >>= 1) {
        if (str == 64) {
          bool up = ((i0 & len) == 0);
          uint64_t mn = (v0 < v1) ? v0 : v1;
          uint64_t mx = (v0 < v1) ? v1 : v0;
          v0 = up ? mn : mx; v1 = up ? mx : mn;
        } else {
          v0 = cex64(v0, i0, len, str, lane);
          v1 = cex64(v1, i1, len, str, lane);
        }
      }
    }
    sk[i0] = v0; sk[i1] = v1;
  }
  __syncthreads();

  // Phase 2: levels len=256..2048 — LDS passes for str>=128, register tail
  for (int len = 256; len <= CAND_CAP; len <<= 1) {
    for (int str = len >> 1; str >= 128; str >>= 1) {
      for (int i = tid; i < CAND_CAP; i += 1024) {
        int j = i ^ str;
        if (j > i) {
          bool up = ((i & len) == 0);
          uint64_t x = sk[i], y = sk[j];
          if ((x > y) == up) { sk[i] = y; sk[j] = x; }
        }
      }
      __syncthreads();
    }
    {
      uint64_t v0 = sk[i0], v1 = sk[i1];
      bool up = ((i0 & len) == 0);       // str=64: intra-thread pair
      uint64_t mn = (v0 < v1) ? v0 : v1;
      uint64_t mx = (v0 < v1) ? v1 : v0;
      v0 = up ? mn : mx; v1 = up ? mx : mn;
      #pragma unroll
      for (int str = 32; str > 0; str >>= 1) {
        v0 = cex64(v0, i0, len, str, lane);
        v1 = cex64(v1, i1, len, str, lane);
      }
      sk[i0] = v0; sk[i1] = v1;
    }
    __syncthreads();
  }

  // ---- decode entry `tid` (rank tid, descending) ----
  if (tid < KTOP) {
#pragma clang fp contract(off)
    int t = n*KTOP + tid;
    uint64_t key = sk[CAND_CAP-1-tid];
    uint32_t idx = ~(uint32_t)(key & 0xFFFFFFFFull);
    float s = __uint_as_float((uint32_t)(key >> 32));
    int a = idx % AANCH, pos = idx / AANCH;
    int w = pos % WDIM, h = pos / WDIM;
    float d[5], an[5];
    #pragma unroll
    for (int j = 0; j < 5; ++j)
      d[j] = breg[((n*(AANCH*5) + (a*5+j))*HDIM + h)*WDIM + w];
    #pragma unroll
    for (int j = 0; j < 5; ++j)
      an[j] = anch[((size_t)n*MTOT + idx)*5 + j];
    const float CLIP = 4.135166556742356f;           // log(1000/16)
    float dw = fminf(d[2], CLIP), dh = fminf(d[3], CLIP);
    float x  = d[0]*an[2] + an[0];
    float y  = d[1]*an[3] + an[1];
    float bw = expf(dw)*an[2];
    float bh = expf(dh)*an[3];
    float th = an[4] + d[4]*57.29577951308232f;      // 180/pi
    prop[t*5+0]=x; prop[t*5+1]=y; prop[t*5+2]=bw; prop[t*5+3]=bh; prop[t*5+4]=th;
    score[t] = s;
    validf[t] = (bw >= 4.0f && bh >= 4.0f) ? 1u : 0u;
    area[t] = bw*bh;
    float r = 0.5f*sqrtf(bw*bw + bh*bh);
    xyr[t] = make_float4(x, y, r, 0.0f);
    float ang = th * 0.017453292519943295f;          // pi/180
    float cs = cosf(ang), sn = sinf(ang);
    float hw2 = bw*0.5f, hh2 = bh*0.5f;
    const float sx[4] = {1.f,-1.f,-1.f,1.f};
    const float sy[4] = {1.f,1.f,-1.f,-1.f};
    #pragma unroll
    for (int k = 0; k < 4; ++k) {
      float dxk = sx[k]*hw2, dyk = sy[k]*hh2;
      float cx = (x + cs*dxk) - sn*dyk;
      float cy = (y + sn*dxk) + cs*dyk;
      corn[t*8 + k*2 + 0] = cx;
      corn[t*8 + k*2 + 1] = cy;
    }
  }
}

// ---------------- Sutherland-Hodgman, register-resident ----------------
__device__ __forceinline__ float quad_inter_area(const float* __restrict__ ca,
                                                 const float* __restrict__ cb) {
#pragma clang fp contract(off)
  float px[8], py[8];
  int n = 4;
  #pragma unroll
  for (int i = 0; i < 4; ++i) { px[i] = ca[2*i]; py[i] = ca[2*i+1]; }
  #pragma unroll
  for (int i = 4; i < 8; ++i) { px[i] = 0.0f; py[i] = 0.0f; }
  #pragma unroll
  for (int e = 0; e < 4; ++e) {
    float p1x = cb[2*e], p1y = cb[2*e+1];
    int e2 = (e+1)&3;
    float dx = cb[2*e2] - p1x, dy = cb[2*e2+1] - p1y;
    float sd[8];
    #pragma unroll
    for (int i = 0; i < 8; ++i)
      sd[i] = dx*(py[i]-p1y) - dy*(px[i]-p1x);   // only i<n consumed
    float qx[8], qy[8];
    #pragma unroll
    for (int i = 0; i < 8; ++i) { qx[i] = 0.0f; qy[i] = 0.0f; }
    int m = 0;
    #pragma unroll
    for (int i = 0; i < 8; ++i) {
      if (i < n) {
        bool wrap = !(i+1 < n);
        float sdi = sd[i];
        float sdn = wrap ? sd[0] : sd[(i+1)&7];
        float pnx = wrap ? px[0] : px[(i+1)&7];
        float pny = wrap ? py[0] : py[(i+1)&7];
        bool ini = sdi >= 0.0f, inn = sdn >= 0.0f;
        if (ini) {
          float vx = px[i], vy = py[i];
          #pragma unroll
          for (int k = 0; k < 8; ++k) if (m == k) { qx[k] = vx; qy[k] = vy; }
          ++m;
        }
        if (ini != inn) {
          float den = sdi - sdn;
          float dd = (fabsf(den) < 1e-12f) ? 1e-12f : den;
          float tt = sdi/dd;
          float vx = px[i] + tt*(pnx - px[i]);
          float vy = py[i] + tt*(pny - py[i]);
          #pragma unroll
          for (int k = 0; k < 8; ++k) if (m == k) { qx[k] = vx; qy[k] = vy; }
          ++m;
        }
      }
    }
    n = m;
    #pragma unroll
    for (int i = 0; i < 8; ++i) { px[i] = qx[i]; py[i] = qy[i]; }
  }
  float ssum = 0.0f;
  #pragma unroll
  for (int i = 0; i < 8; ++i) {
    if (i < n) {
      bool wrap = !(i+1 < n);
      float pnx = wrap ? px[0] : px[(i+1)&7];
      float pny = wrap ? py[0] : py[(i+1)&7];
      ssum += px[i]*pny - pnx*py[i];
    }
  }
  return 0.5f*fabsf(ssum);
}

// ---------------- fused circle-test + clip; xyr staged in LDS; 4 rows/block ----------------
__global__ __launch_bounds__(256) void k_iou(const float4* __restrict__ xyr,
                                             const float* __restrict__ corn,
                                             const float* __restrict__ area,
                                             uint64_t* __restrict__ maskT) {
  __shared__ float4 sxyr[KTOP];            // 16000 B, this batch's boxes
  __shared__ uint32_t q[QCAP];             // 16384 B
  __shared__ uint32_t qcnt;
  __shared__ uint32_t mrow32[IOU_WPB*2];   // 4 rows x 16 words x 2 halves
  __shared__ float ca[IOU_ROWS*8];         // own rows' corners
  __shared__ float aa[IOU_ROWS];
  int n = blockIdx.x / IOU_BPB;
  int wbase = (blockIdx.x % IOU_BPB) * IOU_WPB;
  int i0 = wbase >> 4;                     // first owned i-row
  int tid = threadIdx.x, wv = tid >> 6, lane = tid & 63;
  // stage
  for (int t = tid; t < KTOP; t += 256) sxyr[t] = xyr[n*KTOP + t];
  if (tid == 0) qcnt = 0;
  if (tid < IOU_WPB*2) mrow32[tid] = 0;
  if (tid >= 128 && tid < 128 + IOU_ROWS*8)
    ca[tid-128] = corn[(size_t)(n*KTOP + i0)*8 + (tid-128)];
  if (tid >= 160 && tid < 160 + IOU_ROWS)
    aa[tid-160] = area[n*KTOP + i0 + (tid-160)];
  __syncthreads();
  // scan: 16 words per wave, all LDS reads
  for (int w = wv; w < IOU_WPB; w += 4) {
    int word = wbase + w;
    int i = word >> 4;               // word / NWORDS
    int jb = word & 15;              // word % NWORDS
    if (jb*64 + 63 <= i) continue;   // no j > i in this word
    int j = jb*64 + lane;
    bool hit = false;
    if (j > i && j < KTOP) {
      float4 a = sxyr[i];            // wave-uniform LDS broadcast
      float4 b = sxyr[j];
      float dx = a.x - b.x, dy = a.y - b.y;
      float rs = a.z + b.z;
      hit = (dx*dx + dy*dy) <= rs*rs*1.0001f;
    }
    unsigned long long bal = __ballot(hit);
    if (!bal) continue;
    int tot = __popcll(bal);
    int leader = __ffsll(bal) - 1;
    uint32_t base = 0;
    if (lane == leader) base = atomicAdd(&qcnt, (uint32_t)tot);
    base = __shfl(base, leader);
    if (hit) {
      int pos = __popcll(bal & ((1ull << lane) - 1ull));
      q[base + pos] = ((uint32_t)i << 10) | (uint32_t)j;
    }
  }
  __syncthreads();
  uint32_t cnt = qcnt;
  for (uint32_t t = tid; t < cnt; t += 256) {
    uint32_t code = q[t];
    int i = code >> 10, j = code & 1023;
    int bj = n*KTOP + j;
    float inter = quad_inter_area(&ca[(i - i0)*8], &corn[(size_t)bj*8]);
    float uni = (aa[i - i0] + area[bj]) - inter;
    if (inter / fmaxf(uni, 1e-8f) > NMS_TH)
      atomicOr(&mrow32[((i - i0)*NWORDS + (j >> 6))*2 + ((j >> 5) & 1)],
               1u << (j & 31));
  }
  __syncthreads();
  // store transposed: maskT[n][l][row] (disjoint cells, full overwrite)
  uint64_t* dstT = &maskT[(size_t)n*NWORDS*KTOP];
  for (int t = tid; t < IOU_WPB; t += 256) {
    int r = t >> 4, l = t & 15;
    dstT[(size_t)l*KTOP + i0 + r] =
      (uint64_t)mrow32[(r*NWORDS + l)*2] | ((uint64_t)mrow32[(r*NWORDS + l)*2 + 1] << 32);
  }
}

// ---------------- greedy NMS via exact Jacobi fixpoint iteration ----------------
__global__ __launch_bounds__(1024) void k_nms(const uint32_t* __restrict__ validf,
                                              const uint64_t* __restrict__ maskT,
                                              const float* __restrict__ prop,
                                              const float* __restrict__ score,
                                              float* __restrict__ out) {
  __shared__ uint64_t sm[NWORDS*KTOP];   // 128000 B: sm[l*KTOP+row]
  __shared__ uint64_t kwA[NWORDS];       // current alive words
  __shared__ uint64_t vw[NWORDS];        // valid words (constant)
  __shared__ int changed;
  int n = blockIdx.x;
  int tid = threadIdx.x, wv = tid >> 6, lane = tid & 63;
  const uint64_t* MT = &maskT[(size_t)n*NWORDS*KTOP];
  for (int g = tid; g < NWORDS*KTOP; g += 1024) sm[g] = MT[g];
  if (wv == 0) {
    #pragma unroll
    for (int w = 0; w < NWORDS; ++w) {
      int k = w*64 + lane;
      uint32_t v = (k < KTOP) ? validf[n*KTOP + k] : 0u;
      unsigned long long bm = __ballot(v != 0u);
      if (lane == 0) { vw[w] = (uint64_t)bm; kwA[w] = (uint64_t)bm; }
    }
  }
  __syncthreads();

  int l = wv;   // 16 waves <-> 16 words
  for (int it = 0; it < 1024; ++it) {
    if (tid == 0) changed = 0;
    uint64_t acc = 0;
    #pragma unroll
    for (int k = 0; k < NWORDS; ++k) {
      int row = k*64 + lane;
      uint64_t aw = kwA[k];                       // LDS broadcast
      uint64_t mrow = (row < KTOP) ? sm[l*KTOP + row] : 0ull;
      uint64_t bit = (aw >> lane) & 1ull;
      acc |= mrow & ((uint64_t)0 - bit);
    }
    #pragma unroll
    for (int s = 1; s < 64; s <<= 1) acc |= __shfl_xor(acc, s);
    uint64_t newl = vw[l] & ~acc;
    __syncthreads();                              // all kwA reads done; changed reset visible
    if (lane == 0) {
      if (newl != kwA[l]) changed = 1;            // benign write race (all write 1)
      kwA[l] = newl;
    }
    __syncthreads();
    if (!changed) break;
  }

  if (tid == 0) {
    int prev = 0;
    #pragma unroll
    for (int t = 0; t < NWORDS; ++t) {
      uint64_t wrd = kwA[t];
      int pc = __popcll(wrd);
      if (prev >= POSTN) wrd = 0;
      else if (prev + pc > POSTN) {
        int allow = POSTN - prev;
        while (__popcll(wrd) > allow) wrd &= ~(1ull << (63 - __clzll(wrd)));
      }
      prev += __popcll(wrd);
      kwA[t] = wrd;
    }
  }
  __syncthreads();
  for (int k = tid; k < KTOP; k += 1024) {
    bool bb = (kwA[k>>6] >> (k&63)) & 1ull;
    float f = bb ? 1.0f : 0.0f;
    int t = n*KTOP + k;
    #pragma unroll
    for (int c = 0; c < 5; ++c) out[t*6 + c] = prop[t*5 + c] * f;
    out[t*6 + 5] = score[t] * f;
  }
}

extern "C" void kernel_launch(void* const* d_in, const int* in_sizes, int n_in,
                              void* d_out, int out_size, void* d_ws, size_t ws_size,
                              hipStream_t stream) {
  const float* obj  = (const float*)d_in[0];
  const float* breg = (const float*)d_in[1];
  const float* anch = (const float*)d_in[2];
  float* out = (float*)d_out;
  char* ws = (char*)d_ws;

  uint32_t* hist   = (uint32_t*)(ws + OFF_HIST);
  uint32_t* cnt    = (uint32_t*)(ws + OFF_CNT);
  uint32_t* thr    = (uint32_t*)(ws + OFF_THR);
  uint32_t* done_h = (uint32_t*)(ws + OFF_THR + 64);
  uint64_t* cand   = (uint64_t*)(ws + OFF_CAND);
  float*    prop   = (float*)(ws + OFF_PROP);
  float*    score  = (float*)(ws + OFF_SCORE);
  float*    corn   = (float*)(ws + OFF_CORN);
  float*    area   = (float*)(ws + OFF_AREA);
  uint32_t* validf = (uint32_t*)(ws + OFF_VALID);
  float4*   xyr    = (float4*)(ws + OFF_XYR);
  uint64_t* maskT  = (uint64_t*)(ws + OFF_MASK);

  k_zero   <<<(ZERO_U4+255)/256, 256, 0, stream>>>((uint4*)ws);
  k_hist   <<<NBATCH*BPB, 256, 0, stream>>>(obj, hist, thr, done_h);
  k_compact<<<NBATCH*CBLK, 256, 0, stream>>>(obj, thr, cand, cnt);
  k_sortdec<<<NBATCH, 1024, 0, stream>>>(cand, cnt, breg, anch, prop, score, corn, area, xyr, validf);
  k_iou    <<<NBATCH*IOU_BPB, 256, 0, stream>>>(xyr, corn, area, maskT);
  k_nms    <<<NBATCH, 1024, 0, stream>>>(validf, maskT, prop, score, out);
}

// Round 20
// 109.074 us; speedup vs baseline: 1.9547x; 1.1387x over previous
//
#include <hip/hip_runtime.h>
#include <stdint.h>

// RPN rotated-NMS post-processor, MI355X. Round 20: un-fuse thresh from hist
// (r16->r18 ledger showed fusion cost ~20us via VGPR bloat + critical-path
// tail). Keeps r19's 8192-bin hist + vectorized thresh scan. 7 nodes.

#define NBATCH 4
#define AANCH 15
#define HDIM 200
#define WDIM 200
#define MTOT (AANCH*HDIM*WDIM)   // 600000
#define KTOP 1000
#define POSTN 300
#define NBINS 8192               // sigmoid bits >> 17
#define CAND_CAP 2048
#define NWORDS 16                // ceil(1000/64)
#define NMS_TH 0.7f
#define BPB 75                   // blocks per batch for hist
#define CHUNK (MTOT/BPB)         // 8000
#define IOU_ROWS 4               // i-rows per iou block
#define IOU_BPB 250              // iou blocks per batch
#define IOU_WPB (IOU_ROWS*NWORDS) // 64 mask words per iou block
#define QCAP 4096                // provable max survivors (4 rows x <=1000 j)
#define NQ4 (MTOT/4)             // 150000 float4 per batch
#define CBLK ((NQ4+255)/256)     // 586 compact blocks per batch

// ---------------- ws layout ----------------
constexpr size_t OFF_HIST = 0;
constexpr size_t SZ_HIST  = (size_t)NBATCH*NBINS*4;                 // 131072
constexpr size_t OFF_CNT  = OFF_HIST + SZ_HIST;
constexpr size_t OFF_THR  = OFF_CNT + 256;
constexpr size_t OFF_CAND = OFF_THR + 256;                          // zeroed prefix
constexpr size_t OFF_PROP = OFF_CAND + (size_t)NBATCH*CAND_CAP*8;
constexpr size_t OFF_SCORE= OFF_PROP + (size_t)NBATCH*KTOP*5*4;
constexpr size_t OFF_CORN = OFF_SCORE+ (size_t)NBATCH*KTOP*4;
constexpr size_t OFF_AREA = OFF_CORN + (size_t)NBATCH*KTOP*8*4;
constexpr size_t OFF_VALID= OFF_AREA + (size_t)NBATCH*KTOP*4;
constexpr size_t OFF_XYR  = OFF_VALID+ (size_t)NBATCH*KTOP*4;
constexpr size_t OFF_MASK = OFF_XYR  + (size_t)NBATCH*KTOP*16;      // maskT [n][l][row]

constexpr int ZERO_U4 = (int)(OFF_CAND / 16);

__device__ __forceinline__ float sigmoid_ref(float x) {
  return 1.0f / (1.0f + expf(-x));
}

// ---------------- zero scratch header ----------------
__global__ __launch_bounds__(256) void k_zero(uint4* __restrict__ p) {
  int t = blockIdx.x*256 + threadIdx.x;
  if (t < ZERO_U4) p[t] = make_uint4(0u,0u,0u,0u);
}

// ---------------- histogram: LDS-privatized, thin ----------------
__global__ __launch_bounds__(256) void k_hist(const float* __restrict__ obj,
                                              uint32_t* __restrict__ hist) {
  __shared__ uint32_t h[NBINS];          // 32 KB
  for (int i = threadIdx.x; i < NBINS; i += 256) h[i] = 0;
  __syncthreads();
  int n = blockIdx.x / BPB, c = blockIdx.x % BPB;
  const float4* p = (const float4*)(obj + (size_t)n*MTOT + (size_t)c*CHUNK);
  const int nq = CHUNK/4;
  for (int q = threadIdx.x; q < nq; q += 256) {
    float4 v = p[q];
    #pragma unroll
    for (int k = 0; k < 4; ++k) {
      float x = (&v.x)[k];
      uint32_t bits = __float_as_uint(sigmoid_ref(x));
      uint32_t bin = bits >> 17; if (bin > NBINS-1) bin = NBINS-1;
      atomicAdd(&h[bin], 1u);
    }
  }
  __syncthreads();
  uint32_t* hb = &hist[n*NBINS];
  for (int i = threadIdx.x; i < NBINS; i += 256) {
    uint32_t v = h[i];
    if (v) atomicAdd(&hb[i], v);
  }
}

// ---------------- threshold: vectorized partial sums ----------------
__global__ __launch_bounds__(256) void k_thresh(const uint32_t* __restrict__ hist,
                                                uint32_t* __restrict__ thr) {
  __shared__ uint32_t ps[256];
  int n = blockIdx.x, tid = threadIdx.x;
  const uint32_t* hb = &hist[n*NBINS];
  uint32_t s = 0;
  {
    const uint4* hb4 = (const uint4*)hb;
    #pragma unroll
    for (int u = 0; u < 8; ++u) {
      uint4 v = hb4[tid*8 + u];
      s += v.x + v.y + v.z + v.w;
    }
  }
  ps[tid] = s;
  __syncthreads();
  if (tid == 0) {
    uint32_t cum = 0; int cidx = -1;
    for (int cc = 255; cc >= 0; --cc) {
      if (cum + ps[cc] >= KTOP) { cidx = cc; break; }
      cum += ps[cc];
    }
    if (cidx < 0) { thr[n] = 0u; return; }
    int b = cidx*32+31;
    for (; b >= cidx*32; --b) { cum += hb[b]; if (cum >= KTOP) break; }
    thr[n] = (uint32_t)(b < 0 ? 0 : b);
  }
}

// ---------------- compact: float4 loads + block-aggregated atomic ----------------
__global__ __launch_bounds__(256) void k_compact(const float* __restrict__ obj,
                                                 const uint32_t* __restrict__ thr,
                                                 uint64_t* __restrict__ cand,
                                                 uint32_t* __restrict__ cnt) {
  __shared__ uint32_t wtot[4];
  __shared__ uint32_t gbase;
  int n = blockIdx.x / CBLK, c = blockIdx.x % CBLK;
  int tid = threadIdx.x, wv = tid >> 6, lane = tid & 63;
  int q = c*256 + tid;                 // float4 index within batch
  uint32_t th = thr[n];
  bool hit0=false, hit1=false, hit2=false, hit3=false;
  uint32_t bits[4], fidx[4];
  if (q < NQ4) {
    float4 v = ((const float4*)(obj + (size_t)n*MTOT))[q];
    #pragma unroll
    for (int k = 0; k < 4; ++k) {
      float x = (&v.x)[k];
      uint32_t b = __float_as_uint(sigmoid_ref(x));
      uint32_t bin = b >> 17; if (bin > NBINS-1) bin = NBINS-1;
      bits[k] = b;
      int rem = q*4 + k;               // element index within batch
      int hw = rem % (HDIM*WDIM);
      int a  = rem / (HDIM*WDIM);
      fidx[k] = (uint32_t)(hw*AANCH + a);
      bool hk = (bin >= th);
      if (k == 0) hit0 = hk; else if (k == 1) hit1 = hk;
      else if (k == 2) hit2 = hk; else hit3 = hk;
    }
  }
  unsigned long long m0 = __ballot(hit0);
  unsigned long long m1 = __ballot(hit1);
  unsigned long long m2 = __ballot(hit2);
  unsigned long long m3 = __ballot(hit3);
  if (lane == 0)
    wtot[wv] = (uint32_t)(__popcll(m0)+__popcll(m1)+__popcll(m2)+__popcll(m3));
  __syncthreads();
  if (tid == 0) {
    uint32_t t0 = wtot[0], t1 = wtot[1], t2 = wtot[2], t3 = wtot[3];
    uint32_t tot = t0+t1+t2+t3;
    gbase = tot ? atomicAdd(&cnt[n], tot) : 0u;
    wtot[0] = 0; wtot[1] = t0; wtot[2] = t0+t1; wtot[3] = t0+t1+t2;
  }
  __syncthreads();
  uint32_t base = gbase + wtot[wv];
  unsigned long long below = (1ull << lane) - 1ull;
  uint32_t off = 0;
  bool hits[4] = {hit0, hit1, hit2, hit3};
  unsigned long long ms[4] = {m0, m1, m2, m3};
  #pragma unroll
  for (int k = 0; k < 4; ++k) {
    if (hits[k]) {
      uint32_t p = base + off + (uint32_t)__popcll(ms[k] & below);
      if (p < CAND_CAP)
        cand[(size_t)n*CAND_CAP + p] = ((uint64_t)bits[k] << 32) | (uint32_t)(~fidx[k]);
    }
    off += (uint32_t)__popcll(ms[k]);
  }
}

// ---------------- register compare-exchange for wave-local bitonic ----------------
__device__ __forceinline__ uint64_t cex64(uint64_t v, int i, int len, int str, int lane) {
  uint64_t p = __shfl_xor(v, str);
  bool up = ((i & len) == 0);
  bool lower = ((lane & str) == 0);
  uint64_t mn = (v < p) ? v : p;
  uint64_t mx = (v < p) ? p : v;
  return (up == lower) ? mn : mx;
}

// ---------------- hybrid bitonic sort (register wave-local phases) + decode ----------------
__global__ __launch_bounds__(1024) void k_sortdec(const uint64_t* __restrict__ cand,
                                                  const uint32_t* __restrict__ cnt,
                                                  const float* __restrict__ breg,
                                                  const float* __restrict__ anch,
                                                  float* __restrict__ prop,
                                                  float* __restrict__ score,
                                                  float* __restrict__ corn,
                                                  float* __restrict__ area,
                                                  float4* __restrict__ xyr,
                                                  uint32_t* __restrict__ validf) {
  __shared__ uint64_t sk[CAND_CAP];
  int n = blockIdx.x, tid = threadIdx.x;
  int lane = tid & 63, wv = tid >> 6;
  uint32_t c = cnt[n]; if (c > CAND_CAP) c = CAND_CAP;
  for (int i = tid; i < CAND_CAP; i += 1024)
    sk[i] = (i < (int)c) ? cand[(size_t)n*CAND_CAP + i] : 0ull;
  __syncthreads();

  const int base = wv * 128;          // wave-owned 128-element chunk
  const int i0 = base + lane;         // slot 0 element index
  const int i1 = base + lane + 64;    // slot 1 element index

  // Phase 1: levels len=2..128 fully in registers (shfl_xor; race-free)
  {
    uint64_t v0 = sk[i0], v1 = sk[i1];
    #pragma unroll
    for (int len = 2; len <= 128; len <<= 1) {
      #pragma unroll
      for (int str = len >> 1; str > 0; str >>= 1) {
        if (str == 64) {
          bool up = ((i0 & len) == 0);
          uint64_t mn = (v0 < v1) ? v0 : v1;
          uint64_t mx = (v0 < v1) ? v1 : v0;
          v0 = up ? mn : mx; v1 = up ? mx : mn;
        } else {
          v0 = cex64(v0, i0, len, str, lane);
          v1 = cex64(v1, i1, len, str, lane);
        }
      }
    }
    sk[i0] = v0; sk[i1] = v1;
  }
  __syncthreads();

  // Phase 2: levels len=256..2048 — LDS passes for str>=128, register tail
  for (int len = 256; len <= CAND_CAP; len <<= 1) {
    for (int str = len >> 1; str >= 128; str >>= 1) {
      for (int i = tid; i < CAND_CAP; i += 1024) {
        int j = i ^ str;
        if (j > i) {
          bool up = ((i & len) == 0);
          uint64_t x = sk[i], y = sk[j];
          if ((x > y) == up) { sk[i] = y; sk[j] = x; }
        }
      }
      __syncthreads();
    }
    {
      uint64_t v0 = sk[i0], v1 = sk[i1];
      bool up = ((i0 & len) == 0);       // str=64: intra-thread pair
      uint64_t mn = (v0 < v1) ? v0 : v1;
      uint64_t mx = (v0 < v1) ? v1 : v0;
      v0 = up ? mn : mx; v1 = up ? mx : mn;
      #pragma unroll
      for (int str = 32; str > 0; str >>= 1) {
        v0 = cex64(v0, i0, len, str, lane);
        v1 = cex64(v1, i1, len, str, lane);
      }
      sk[i0] = v0; sk[i1] = v1;
    }
    __syncthreads();
  }

  // ---- decode entry `tid` (rank tid, descending) ----
  if (tid < KTOP) {
#pragma clang fp contract(off)
    int t = n*KTOP + tid;
    uint64_t key = sk[CAND_CAP-1-tid];
    uint32_t idx = ~(uint32_t)(key & 0xFFFFFFFFull);
    float s = __uint_as_float((uint32_t)(key >> 32));
    int a = idx % AANCH, pos = idx / AANCH;
    int w = pos % WDIM, h = pos / WDIM;
    float d[5], an[5];
    #pragma unroll
    for (int j = 0; j < 5; ++j)
      d[j] = breg[((n*(AANCH*5) + (a*5+j))*HDIM + h)*WDIM + w];
    #pragma unroll
    for (int j = 0; j < 5; ++j)
      an[j] = anch[((size_t)n*MTOT + idx)*5 + j];
    const float CLIP = 4.135166556742356f;           // log(1000/16)
    float dw = fminf(d[2], CLIP), dh = fminf(d[3], CLIP);
    float x  = d[0]*an[2] + an[0];
    float y  = d[1]*an[3] + an[1];
    float bw = expf(dw)*an[2];
    float bh = expf(dh)*an[3];
    float th = an[4] + d[4]*57.29577951308232f;      // 180/pi
    prop[t*5+0]=x; prop[t*5+1]=y; prop[t*5+2]=bw; prop[t*5+3]=bh; prop[t*5+4]=th;
    score[t] = s;
    validf[t] = (bw >= 4.0f && bh >= 4.0f) ? 1u : 0u;
    area[t] = bw*bh;
    float r = 0.5f*sqrtf(bw*bw + bh*bh);
    xyr[t] = make_float4(x, y, r, 0.0f);
    float ang = th * 0.017453292519943295f;          // pi/180
    float cs = cosf(ang), sn = sinf(ang);
    float hw2 = bw*0.5f, hh2 = bh*0.5f;
    const float sx[4] = {1.f,-1.f,-1.f,1.f};
    const float sy[4] = {1.f,1.f,-1.f,-1.f};
    #pragma unroll
    for (int k = 0; k < 4; ++k) {
      float dxk = sx[k]*hw2, dyk = sy[k]*hh2;
      float cx = (x + cs*dxk) - sn*dyk;
      float cy = (y + sn*dxk) + cs*dyk;
      corn[t*8 + k*2 + 0] = cx;
      corn[t*8 + k*2 + 1] = cy;
    }
  }
}

// ---------------- Sutherland-Hodgman, register-resident ----------------
__device__ __forceinline__ float quad_inter_area(const float* __restrict__ ca,
                                                 const float* __restrict__ cb) {
#pragma clang fp contract(off)
  float px[8], py[8];
  int n = 4;
  #pragma unroll
  for (int i = 0; i < 4; ++i) { px[i] = ca[2*i]; py[i] = ca[2*i+1]; }
  #pragma unroll
  for (int i = 4; i < 8; ++i) { px[i] = 0.0f; py[i] = 0.0f; }
  #pragma unroll
  for (int e = 0; e < 4; ++e) {
    float p1x = cb[2*e], p1y = cb[2*e+1];
    int e2 = (e+1)&3;
    float dx = cb[2*e2] - p1x, dy = cb[2*e2+1] - p1y;
    float sd[8];
    #pragma unroll
    for (int i = 0; i < 8; ++i)
      sd[i] = dx*(py[i]-p1y) - dy*(px[i]-p1x);   // only i<n consumed
    float qx[8], qy[8];
    #pragma unroll
    for (int i = 0; i < 8; ++i) { qx[i] = 0.0f; qy[i] = 0.0f; }
    int m = 0;
    #pragma unroll
    for (int i = 0; i < 8; ++i) {
      if (i < n) {
        bool wrap = !(i+1 < n);
        float sdi = sd[i];
        float sdn = wrap ? sd[0] : sd[(i+1)&7];
        float pnx = wrap ? px[0] : px[(i+1)&7];
        float pny = wrap ? py[0] : py[(i+1)&7];
        bool ini = sdi >= 0.0f, inn = sdn >= 0.0f;
        if (ini) {
          float vx = px[i], vy = py[i];
          #pragma unroll
          for (int k = 0; k < 8; ++k) if (m == k) { qx[k] = vx; qy[k] = vy; }
          ++m;
        }
        if (ini != inn) {
          float den = sdi - sdn;
          float dd = (fabsf(den) < 1e-12f) ? 1e-12f : den;
          float tt = sdi/dd;
          float vx = px[i] + tt*(pnx - px[i]);
          float vy = py[i] + tt*(pny - py[i]);
          #pragma unroll
          for (int k = 0; k < 8; ++k) if (m == k) { qx[k] = vx; qy[k] = vy; }
          ++m;
        }
      }
    }
    n = m;
    #pragma unroll
    for (int i = 0; i < 8; ++i) { px[i] = qx[i]; py[i] = qy[i]; }
  }
  float ssum = 0.0f;
  #pragma unroll
  for (int i = 0; i < 8; ++i) {
    if (i < n) {
      bool wrap = !(i+1 < n);
      float pnx = wrap ? px[0] : px[(i+1)&7];
      float pny = wrap ? py[0] : py[(i+1)&7];
      ssum += px[i]*pny - pnx*py[i];
    }
  }
  return 0.5f*fabsf(ssum);
}

// ---------------- fused circle-test + clip; xyr staged in LDS; 4 rows/block ----------------
__global__ __launch_bounds__(256) void k_iou(const float4* __restrict__ xyr,
                                             const float* __restrict__ corn,
                                             const float* __restrict__ area,
                                             uint64_t* __restrict__ maskT) {
  __shared__ float4 sxyr[KTOP];            // 16000 B, this batch's boxes
  __shared__ uint32_t q[QCAP];             // 16384 B
  __shared__ uint32_t qcnt;
  __shared__ uint32_t mrow32[IOU_WPB*2];   // 4 rows x 16 words x 2 halves
  __shared__ float ca[IOU_ROWS*8];         // own rows' corners
  __shared__ float aa[IOU_ROWS];
  int n = blockIdx.x / IOU_BPB;
  int wbase = (blockIdx.x % IOU_BPB) * IOU_WPB;
  int i0 = wbase >> 4;                     // first owned i-row
  int tid = threadIdx.x, wv = tid >> 6, lane = tid & 63;
  // stage
  for (int t = tid; t < KTOP; t += 256) sxyr[t] = xyr[n*KTOP + t];
  if (tid == 0) qcnt = 0;
  if (tid < IOU_WPB*2) mrow32[tid] = 0;
  if (tid >= 128 && tid < 128 + IOU_ROWS*8)
    ca[tid-128] = corn[(size_t)(n*KTOP + i0)*8 + (tid-128)];
  if (tid >= 160 && tid < 160 + IOU_ROWS)
    aa[tid-160] = area[n*KTOP + i0 + (tid-160)];
  __syncthreads();
  // scan: 16 words per wave, all LDS reads
  for (int w = wv; w < IOU_WPB; w += 4) {
    int word = wbase + w;
    int i = word >> 4;               // word / NWORDS
    int jb = word & 15;              // word % NWORDS
    if (jb*64 + 63 <= i) continue;   // no j > i in this word
    int j = jb*64 + lane;
    bool hit = false;
    if (j > i && j < KTOP) {
      float4 a = sxyr[i];            // wave-uniform LDS broadcast
      float4 b = sxyr[j];
      float dx = a.x - b.x, dy = a.y - b.y;
      float rs = a.z + b.z;
      hit = (dx*dx + dy*dy) <= rs*rs*1.0001f;
    }
    unsigned long long bal = __ballot(hit);
    if (!bal) continue;
    int tot = __popcll(bal);
    int leader = __ffsll(bal) - 1;
    uint32_t base = 0;
    if (lane == leader) base = atomicAdd(&qcnt, (uint32_t)tot);
    base = __shfl(base, leader);
    if (hit) {
      int pos = __popcll(bal & ((1ull << lane) - 1ull));
      q[base + pos] = ((uint32_t)i << 10) | (uint32_t)j;
    }
  }
  __syncthreads();
  uint32_t cnt = qcnt;
  for (uint32_t t = tid; t < cnt; t += 256) {
    uint32_t code = q[t];
    int i = code >> 10, j = code & 1023;
    int bj = n*KTOP + j;
    float inter = quad_inter_area(&ca[(i - i0)*8], &corn[(size_t)bj*8]);
    float uni = (aa[i - i0] + area[bj]) - inter;
    if (inter / fmaxf(uni, 1e-8f) > NMS_TH)
      atomicOr(&mrow32[((i - i0)*NWORDS + (j >> 6))*2 + ((j >> 5) & 1)],
               1u << (j & 31));
  }
  __syncthreads();
  // store transposed: maskT[n][l][row] (disjoint cells, full overwrite)
  uint64_t* dstT = &maskT[(size_t)n*NWORDS*KTOP];
  for (int t = tid; t < IOU_WPB; t += 256) {
    int r = t >> 4, l = t & 15;
    dstT[(size_t)l*KTOP + i0 + r] =
      (uint64_t)mrow32[(r*NWORDS + l)*2] | ((uint64_t)mrow32[(r*NWORDS + l)*2 + 1] << 32);
  }
}

// ---------------- greedy NMS via exact Jacobi fixpoint iteration ----------------
__global__ __launch_bounds__(1024) void k_nms(const uint32_t* __restrict__ validf,
                                              const uint64_t* __restrict__ maskT,
                                              const float* __restrict__ prop,
                                              const float* __restrict__ score,
                                              float* __restrict__ out) {
  __shared__ uint64_t sm[NWORDS*KTOP];   // 128000 B: sm[l*KTOP+row]
  __shared__ uint64_t kwA[NWORDS];       // current alive words
  __shared__ uint64_t vw[NWORDS];        // valid words (constant)
  __shared__ int changed;
  int n = blockIdx.x;
  int tid = threadIdx.x, wv = tid >> 6, lane = tid & 63;
  const uint64_t* MT = &maskT[(size_t)n*NWORDS*KTOP];
  for (int g = tid; g < NWORDS*KTOP; g += 1024) sm[g] = MT[g];
  if (wv == 0) {
    #pragma unroll
    for (int w = 0; w < NWORDS; ++w) {
      int k = w*64 + lane;
      uint32_t v = (k < KTOP) ? validf[n*KTOP + k] : 0u;
      unsigned long long bm = __ballot(v != 0u);
      if (lane == 0) { vw[w] = (uint64_t)bm; kwA[w] = (uint64_t)bm; }
    }
  }
  __syncthreads();

  int l = wv;   // 16 waves <-> 16 words
  for (int it = 0; it < 1024; ++it) {
    if (tid == 0) changed = 0;
    uint64_t acc = 0;
    #pragma unroll
    for (int k = 0; k < NWORDS; ++k) {
      int row = k*64 + lane;
      uint64_t aw = kwA[k];                       // LDS broadcast
      uint64_t mrow = (row < KTOP) ? sm[l*KTOP + row] : 0ull;
      uint64_t bit = (aw >> lane) & 1ull;
      acc |= mrow & ((uint64_t)0 - bit);
    }
    #pragma unroll
    for (int s = 1; s < 64; s <<= 1) acc |= __shfl_xor(acc, s);
    uint64_t newl = vw[l] & ~acc;
    __syncthreads();                              // all kwA reads done; changed reset visible
    if (lane == 0) {
      if (newl != kwA[l]) changed = 1;            // benign write race (all write 1)
      kwA[l] = newl;
    }
    __syncthreads();
    if (!changed) break;
  }

  if (tid == 0) {
    int prev = 0;
    #pragma unroll
    for (int t = 0; t < NWORDS; ++t) {
      uint64_t wrd = kwA[t];
      int pc = __popcll(wrd);
      if (prev >= POSTN) wrd = 0;
      else if (prev + pc > POSTN) {
        int allow = POSTN - prev;
        while (__popcll(wrd) > allow) wrd &= ~(1ull << (63 - __clzll(wrd)));
      }
      prev += __popcll(wrd);
      kwA[t] = wrd;
    }
  }
  __syncthreads();
  for (int k = tid; k < KTOP; k += 1024) {
    bool bb = (kwA[k>>6] >> (k&63)) & 1ull;
    float f = bb ? 1.0f : 0.0f;
    int t = n*KTOP + k;
    #pragma unroll
    for (int c = 0; c < 5; ++c) out[t*6 + c] = prop[t*5 + c] * f;
    out[t*6 + 5] = score[t] * f;
  }
}

extern "C" void kernel_launch(void* const* d_in, const int* in_sizes, int n_in,
                              void* d_out, int out_size, void* d_ws, size_t ws_size,
                              hipStream_t stream) {
  const float* obj  = (const float*)d_in[0];
  const float* breg = (const float*)d_in[1];
  const float* anch = (const float*)d_in[2];
  float* out = (float*)d_out;
  char* ws = (char*)d_ws;

  uint32_t* hist   = (uint32_t*)(ws + OFF_HIST);
  uint32_t* cnt    = (uint32_t*)(ws + OFF_CNT);
  uint32_t* thr    = (uint32_t*)(ws + OFF_THR);
  uint64_t* cand   = (uint64_t*)(ws + OFF_CAND);
  float*    prop   = (float*)(ws + OFF_PROP);
  float*    score  = (float*)(ws + OFF_SCORE);
  float*    corn   = (float*)(ws + OFF_CORN);
  float*    area   = (float*)(ws + OFF_AREA);
  uint32_t* validf = (uint32_t*)(ws + OFF_VALID);
  float4*   xyr    = (float4*)(ws + OFF_XYR);
  uint64_t* maskT  = (uint64_t*)(ws + OFF_MASK);

  k_zero   <<<(ZERO_U4+255)/256, 256, 0, stream>>>((uint4*)ws);
  k_hist   <<<NBATCH*BPB, 256, 0, stream>>>(obj, hist);
  k_thresh <<<NBATCH, 256, 0, stream>>>(hist, thr);
  k_compact<<<NBATCH*CBLK, 256, 0, stream>>>(obj, thr, cand, cnt);
  k_sortdec<<<NBATCH, 1024, 0, stream>>>(cand, cnt, breg, anch, prop, score, corn, area, xyr, validf);
  k_iou    <<<NBATCH*IOU_BPB, 256, 0, stream>>>(xyr, corn, area, maskT);
  k_nms    <<<NBATCH, 1024, 0, stream>>>(validf, maskT, prop, score, out);
}